// Round 3
// baseline (565.467 us; speedup 1.0000x reference)
//
#include <hip/hip_runtime.h>
#include <stdint.h>

// ---------------- problem constants ----------------
#define N_TOK 8192      // B*S = 4*2048
#define DIM   512       // D
#define HID   1024      // H
#define NE    8         // experts
#define NSLOT 16384     // N_TOK * K (K=2)

typedef __attribute__((ext_vector_type(8))) short short8;   // 8 x bf16 (4 VGPRs) — MFMA A/B frag
typedef __attribute__((ext_vector_type(4))) float f32x4;    // MFMA C/D frag

// ---------------- workspace layout (bytes) ----------------
// w1t [E][H][D] bf16 8.39MB | w2t [E][D][H] bf16 8.39MB | h [NSLOT][H] bf16 33.6MB
// y [NSLOT][D] fp32 33.6MB | topi/topw/slot/rows/rw | cnt[32]
#define W1T_OFF  0ull
#define W2T_OFF  8388608ull
#define H_OFF    16777216ull
#define Y_OFF    50331648ull
#define TOPI_OFF 83886080ull
#define TOPW_OFF 83951616ull
#define SLOT_OFF 84017152ull
#define ROWS_OFF 84082688ull
#define RW_OFF   84148224ull
#define CNT_OFF  84213760ull

__device__ __forceinline__ unsigned int f2bfu(float f) {
  union { float f; unsigned int i; } v; v.f = f;
  unsigned int u = v.i;
  return (u + 0x7FFFu + ((u >> 16) & 1u)) >> 16;  // RNE, returns bf16 bits in low 16
}
__device__ __forceinline__ float bf2f(unsigned int u) {
  union { unsigned int i; float f; } v; v.i = (u & 0xFFFFu) << 16; return v.f;
}

// ================= 1. weight transpose + downcast (+ counter init) =================
// blocks [0,1024): w1 fp32 [E][512][1024] -> w1t bf16 [E][1024][512]
// blocks [1024,2048): w2 fp32 [E][1024][512] -> w2t bf16 [E][512][1024]
__global__ __launch_bounds__(256) void k_transpose(
    const float* __restrict__ w1, const float* __restrict__ w2,
    unsigned short* __restrict__ w1t, unsigned short* __restrict__ w2t,
    int* __restrict__ cnt) {
  if (blockIdx.x == 0 && threadIdx.x < 8) cnt[threadIdx.x] = 0;
  __shared__ unsigned short tile[64][68];   // +4 pad breaks bank conflicts
  int b = blockIdx.x;
  const float* src; unsigned short* dst; int R, C;
  if (b < 1024) { int e = b >> 7; int t = b & 127;
    src = w1 + (size_t)e * 524288; dst = w1t + (size_t)e * 524288; R = 512; C = 1024;
    int tr = t >> 4, tc = t & 15;  // 8 x 16 tiles of 64x64
    src += (size_t)tr * 64 * C + tc * 64; dst += (size_t)tc * 64 * R + tr * 64;
  } else { b -= 1024; int e = b >> 7; int t = b & 127;
    src = w2 + (size_t)e * 524288; dst = w2t + (size_t)e * 524288; R = 1024; C = 512;
    int tr = t >> 3, tc = t & 7;   // 16 x 8 tiles
    src += (size_t)tr * 64 * C + tc * 64; dst += (size_t)tc * 64 * R + tr * 64;
  }
  int tid = threadIdx.x;
#pragma unroll
  for (int i = 0; i < 4; ++i) {
    int l = i * 256 + tid;
    int r = l >> 4, c4 = (l & 15) << 2;
    float4 v = *(const float4*)(src + (size_t)r * C + c4);
    tile[r][c4 + 0] = (unsigned short)f2bfu(v.x);
    tile[r][c4 + 1] = (unsigned short)f2bfu(v.y);
    tile[r][c4 + 2] = (unsigned short)f2bfu(v.z);
    tile[r][c4 + 3] = (unsigned short)f2bfu(v.w);
  }
  __syncthreads();
#pragma unroll
  for (int i = 0; i < 4; ++i) {
    int l = i * 256 + tid;
    int rr = l >> 4, c4 = (l & 15) << 2;
    ushort4 v;
    v.x = tile[c4 + 0][rr]; v.y = tile[c4 + 1][rr]; v.z = tile[c4 + 2][rr]; v.w = tile[c4 + 3][rr];
    *(ushort4*)(dst + (size_t)rr * R + c4) = v;
  }
}

// ================= 2. router: one wave per token (fp32) =================
__global__ __launch_bounds__(256) void k_router(
    const float* __restrict__ x, const float* __restrict__ gw,
    const float* __restrict__ gb, float* __restrict__ probs_out,
    int2* __restrict__ topi, float2* __restrict__ topw, int* __restrict__ cnt) {
  int wave = threadIdx.x >> 6, lane = threadIdx.x & 63;
  int n = blockIdx.x * 4 + wave;
  const float4* xr = (const float4*)(x + (size_t)n * DIM);
  float4 x0 = xr[lane * 2], x1 = xr[lane * 2 + 1];
  float xf[8] = {x0.x, x0.y, x0.z, x0.w, x1.x, x1.y, x1.z, x1.w};
  float acc[8] = {0.f,0.f,0.f,0.f,0.f,0.f,0.f,0.f};
  const float4* gwr = (const float4*)gw;   // row d = 8 fp32 = two float4
#pragma unroll
  for (int j = 0; j < 8; ++j) {
    int d = lane * 8 + j;
    float4 g0 = gwr[d * 2], g1 = gwr[d * 2 + 1];
    acc[0] += xf[j] * g0.x; acc[1] += xf[j] * g0.y; acc[2] += xf[j] * g0.z; acc[3] += xf[j] * g0.w;
    acc[4] += xf[j] * g1.x; acc[5] += xf[j] * g1.y; acc[6] += xf[j] * g1.z; acc[7] += xf[j] * g1.w;
  }
#pragma unroll
  for (int o = 1; o < 64; o <<= 1)
#pragma unroll
    for (int e = 0; e < 8; ++e) acc[e] += __shfl_xor(acc[e], o, 64);
  float p[8], mx = -1e30f, s = 0.f;
#pragma unroll
  for (int e = 0; e < 8; ++e) { p[e] = acc[e] + gb[e]; mx = fmaxf(mx, p[e]); }
#pragma unroll
  for (int e = 0; e < 8; ++e) { p[e] = __expf(p[e] - mx); s += p[e]; }
  float inv = 1.f / s;
#pragma unroll
  for (int e = 0; e < 8; ++e) p[e] *= inv;
  if (lane < 8) probs_out[(size_t)n * NE + lane] = p[lane];
  if (lane == 0) {
    int i0 = 0; float v0 = p[0];
#pragma unroll
    for (int e = 1; e < 8; ++e) if (p[e] > v0) { v0 = p[e]; i0 = e; }   // first-max (jax tie rule)
    int i1 = -1; float v1 = -1.f;
#pragma unroll
    for (int e = 0; e < 8; ++e) if (e != i0 && p[e] > v1) { v1 = p[e]; i1 = e; }
    float sw = 1.f / (v0 + v1);
    topi[n] = make_int2(i0, i1);
    topw[n] = make_float2(v0 * sw, v1 * sw);
    atomicAdd(&cnt[i0], 1); atomicAdd(&cnt[i1], 1);
  }
}

// ================= 3. scan (E=8, trivial) =================
__global__ void k_scan(int* __restrict__ cnt) {
  if (threadIdx.x == 0) {
    int a = 0;
#pragma unroll
    for (int e = 0; e < 8; ++e) { cnt[16 + e] = a; cnt[8 + e] = a; a += cnt[e]; }
    cnt[24] = a;   // = 16384
  }
}

// ================= 4. slot assignment =================
__global__ __launch_bounds__(256) void k_assign(
    const int2* __restrict__ topi, const float2* __restrict__ topw,
    int* __restrict__ cnt, int* __restrict__ rows, float* __restrict__ rw,
    int* __restrict__ slot_of) {
  int n = blockIdx.x * 256 + threadIdx.x;
  if (n >= N_TOK) return;
  int2 ei = topi[n]; float2 wv = topw[n];
  int s0 = atomicAdd(&cnt[8 + ei.x], 1);
  rows[s0] = n; rw[s0] = wv.x; slot_of[2 * n] = s0;
  int s1 = atomicAdd(&cnt[8 + ei.y], 1);
  rows[s1] = n; rw[s1] = wv.y; slot_of[2 * n + 1] = s1;
}

// ================= 5. GEMM1: h = gelu(gather(x) @ w1 + b1), h bf16 =================
// grid.x = E*64 (expert, row-tile), grid.y = 8 (HID col-tile). 128x128 tile, BK=64.
// A staged fp32->bf16 in registers; B (w1t) already bf16.
__global__ __launch_bounds__(256) void k_gemm1(
    const float* __restrict__ x, const unsigned short* __restrict__ w1t,
    const float* __restrict__ b1, const int* __restrict__ offs,
    const int* __restrict__ rows, unsigned short* __restrict__ h) {
  int e = blockIdx.x >> 6, mt = blockIdx.x & 63;
  int off_e = offs[e], cnt_e = offs[e + 1] - off_e;
  if (mt * 128 >= cnt_e) return;
  int nt = blockIdx.y;
  __shared__ __align__(16) unsigned short As[128 * 64];
  __shared__ __align__(16) unsigned short Bs[128 * 64];
  __shared__ int rows_l[128];
  int tid = threadIdx.x;
  if (tid < 128) {
    int r = mt * 128 + tid;
    rows_l[tid] = rows[off_e + (r < cnt_e ? r : cnt_e - 1)];
  }
  __syncthreads();
  int wave = tid >> 6, lane = tid & 63;
  int wr = wave & 1, wc = wave >> 1;
  f32x4 acc[4][4] = {};
  const unsigned short* bBase = w1t + (size_t)e * HID * DIM;

  for (int k0 = 0; k0 < DIM; k0 += 64) {
#pragma unroll
    for (int j = 0; j < 4; ++j) {
      int l = j * 256 + tid;               // 1024 chunks of 8 elements
      int r = l >> 3, c = (l & 7) << 3;
      const float* ap = x + (size_t)rows_l[r] * DIM + k0 + c;
      float4 a0 = *(const float4*)ap, a1 = *(const float4*)(ap + 4);
      uint4 pa;
      pa.x = f2bfu(a0.x) | (f2bfu(a0.y) << 16);
      pa.y = f2bfu(a0.z) | (f2bfu(a0.w) << 16);
      pa.z = f2bfu(a1.x) | (f2bfu(a1.y) << 16);
      pa.w = f2bfu(a1.z) | (f2bfu(a1.w) << 16);
      *(uint4*)&As[r * 64 + c] = pa;
      uint4 vb = *(const uint4*)(bBase + (size_t)(nt * 128 + r) * DIM + k0 + c);
      *(uint4*)&Bs[r * 64 + c] = vb;
    }
    __syncthreads();
#pragma unroll
    for (int kk = 0; kk < 2; ++kk) {
      int ko = kk * 32 + (lane >> 4) * 8;
      short8 a[4], b[4];
#pragma unroll
      for (int m = 0; m < 4; ++m)
        a[m] = *(const short8*)&As[(wr * 64 + m * 16 + (lane & 15)) * 64 + ko];
#pragma unroll
      for (int nb = 0; nb < 4; ++nb)
        b[nb] = *(const short8*)&Bs[(wc * 64 + nb * 16 + (lane & 15)) * 64 + ko];
#pragma unroll
      for (int m = 0; m < 4; ++m)
#pragma unroll
        for (int nb = 0; nb < 4; ++nb)
          acc[m][nb] = __builtin_amdgcn_mfma_f32_16x16x32_bf16(a[m], b[nb], acc[m][nb], 0, 0, 0);
    }
    __syncthreads();
  }
  int rq = (lane >> 4) * 4;
#pragma unroll
  for (int m = 0; m < 4; ++m) {
    int rl = wr * 64 + m * 16 + rq;
#pragma unroll
    for (int nb = 0; nb < 4; ++nb) {
      int col = nt * 128 + wc * 64 + nb * 16 + (lane & 15);
      float bias = b1[e * HID + col];
#pragma unroll
      for (int i = 0; i < 4; ++i) {
        int r = mt * 128 + rl + i;
        if (r < cnt_e) {
          float v = acc[m][nb][i] + bias;
          float g = 0.5f * v * (1.0f + erff(v * 0.70710678118654752f));   // exact GELU
          h[(size_t)(off_e + r) * HID + col] = (unsigned short)f2bfu(g);
        }
      }
    }
  }
}

// ================= 6. GEMM2: y = (h @ w2 + b2) * weight, y fp32 =================
// grid.x = E*64, grid.y = 4 (DIM col-tile). K = HID = 1024. A (h) and B (w2t) bf16.
__global__ __launch_bounds__(256) void k_gemm2(
    const unsigned short* __restrict__ h, const unsigned short* __restrict__ w2t,
    const float* __restrict__ b2, const int* __restrict__ offs,
    const float* __restrict__ rw, float* __restrict__ y) {
  int e = blockIdx.x >> 6, mt = blockIdx.x & 63;
  int off_e = offs[e], cnt_e = offs[e + 1] - off_e;
  if (mt * 128 >= cnt_e) return;
  int nt = blockIdx.y;
  __shared__ __align__(16) unsigned short As[128 * 64];
  __shared__ __align__(16) unsigned short Bs[128 * 64];
  int tid = threadIdx.x;
  int wave = tid >> 6, lane = tid & 63;
  int wr = wave & 1, wc = wave >> 1;
  f32x4 acc[4][4] = {};
  const unsigned short* aBase = h + (size_t)off_e * HID;
  const unsigned short* bBase = w2t + (size_t)e * DIM * HID;
  int rmax = cnt_e - 1;

  for (int k0 = 0; k0 < HID; k0 += 64) {
#pragma unroll
    for (int j = 0; j < 4; ++j) {
      int l = j * 256 + tid;
      int r = l >> 3, c = (l & 7) << 3;
      int ra = mt * 128 + r; if (ra > rmax) ra = rmax;
      uint4 va = *(const uint4*)(aBase + (size_t)ra * HID + k0 + c);
      uint4 vb = *(const uint4*)(bBase + (size_t)(nt * 128 + r) * HID + k0 + c);
      *(uint4*)&As[r * 64 + c] = va;
      *(uint4*)&Bs[r * 64 + c] = vb;
    }
    __syncthreads();
#pragma unroll
    for (int kk = 0; kk < 2; ++kk) {
      int ko = kk * 32 + (lane >> 4) * 8;
      short8 a[4], b[4];
#pragma unroll
      for (int m = 0; m < 4; ++m)
        a[m] = *(const short8*)&As[(wr * 64 + m * 16 + (lane & 15)) * 64 + ko];
#pragma unroll
      for (int nb = 0; nb < 4; ++nb)
        b[nb] = *(const short8*)&Bs[(wc * 64 + nb * 16 + (lane & 15)) * 64 + ko];
#pragma unroll
      for (int m = 0; m < 4; ++m)
#pragma unroll
        for (int nb = 0; nb < 4; ++nb)
          acc[m][nb] = __builtin_amdgcn_mfma_f32_16x16x32_bf16(a[m], b[nb], acc[m][nb], 0, 0, 0);
    }
    __syncthreads();
  }
  int rq = (lane >> 4) * 4;
#pragma unroll
  for (int m = 0; m < 4; ++m) {
    int rl = wr * 64 + m * 16 + rq;
#pragma unroll
    for (int nb = 0; nb < 4; ++nb) {
      int col = nt * 128 + wc * 64 + nb * 16 + (lane & 15);
      float bias = b2[e * DIM + col];
#pragma unroll
      for (int i = 0; i < 4; ++i) {
        int r = mt * 128 + rl + i;
        if (r < cnt_e) {
          float w = rw[off_e + r];
          y[(size_t)(off_e + r) * DIM + col] = (acc[m][nb][i] + bias) * w;
        }
      }
    }
  }
}

// ================= 7. combine: out[n] = y[slot0] + y[slot1] (fp32) =================
__global__ __launch_bounds__(256) void k_combine(
    const float* __restrict__ y, const int* __restrict__ slot_of,
    float* __restrict__ out) {
  int t = blockIdx.x * 256 + threadIdx.x;   // N_TOK*128 threads, 4 fp32 each
  int n = t >> 7, c = (t & 127) << 2;
  int s0 = slot_of[2 * n], s1 = slot_of[2 * n + 1];
  float4 u0 = *(const float4*)(y + (size_t)s0 * DIM + c);
  float4 u1 = *(const float4*)(y + (size_t)s1 * DIM + c);
  float4 o;
  o.x = u0.x + u1.x; o.y = u0.y + u1.y; o.z = u0.z + u1.z; o.w = u0.w + u1.w;
  *(float4*)(out + (size_t)n * DIM + c) = o;
}

// ================= launch =================
extern "C" void kernel_launch(void* const* d_in, const int* in_sizes, int n_in,
                              void* d_out, int out_size, void* d_ws, size_t ws_size,
                              hipStream_t stream) {
  const float* x  = (const float*)d_in[0];
  const float* gw = (const float*)d_in[1];
  const float* gb = (const float*)d_in[2];
  const float* w1 = (const float*)d_in[3];
  const float* b1 = (const float*)d_in[4];
  const float* w2 = (const float*)d_in[5];
  const float* b2 = (const float*)d_in[6];
  float* out = (float*)d_out;
  char* ws = (char*)d_ws;

  unsigned short* w1t = (unsigned short*)(ws + W1T_OFF);
  unsigned short* w2t = (unsigned short*)(ws + W2T_OFF);
  unsigned short* h   = (unsigned short*)(ws + H_OFF);
  float*          y   = (float*)(ws + Y_OFF);
  int2*   topi    = (int2*)(ws + TOPI_OFF);
  float2* topw    = (float2*)(ws + TOPW_OFF);
  int*    slot_of = (int*)(ws + SLOT_OFF);
  int*    rows    = (int*)(ws + ROWS_OFF);
  float*  rw      = (float*)(ws + RW_OFF);
  int*    cnt     = (int*)(ws + CNT_OFF);
  float*  probs   = out + (size_t)N_TOK * DIM;   // outputs: [out | probs]

  k_transpose<<<dim3(2048), dim3(256), 0, stream>>>(w1, w2, w1t, w2t, cnt);
  k_router   <<<dim3(2048), dim3(256), 0, stream>>>(x, gw, gb, probs, topi, topw, cnt);
  k_scan     <<<dim3(1),    dim3(64),  0, stream>>>(cnt);
  k_assign   <<<dim3(32),   dim3(256), 0, stream>>>(topi, topw, cnt, rows, rw, slot_of);
  k_gemm1    <<<dim3(512, 8), dim3(256), 0, stream>>>(x, w1t, b1, cnt + 16, rows, h);
  k_gemm2    <<<dim3(512, 4), dim3(256), 0, stream>>>(h, w2t, b2, cnt + 16, rw, y);
  k_combine  <<<dim3(4096), dim3(256), 0, stream>>>(y, slot_of, out);
}

// Round 4
// 302.290 us; speedup vs baseline: 1.8706x; 1.8706x over previous
//
#include <hip/hip_runtime.h>
#include <stdint.h>

// ---------------- problem constants ----------------
#define N_TOK 8192      // B*S = 4*2048
#define DIM   512       // D
#define HID   1024      // H
#define NE    8         // experts
#define NSLOT 16384     // N_TOK * K (K=2)

typedef __attribute__((ext_vector_type(8))) short short8;   // 8 x bf16 (4 VGPRs) — MFMA A/B frag
typedef __attribute__((ext_vector_type(4))) float f32x4;    // MFMA C/D frag

// ---------------- workspace layout (bytes) ----------------
// w1t [E][H][D] bf16 8.39MB | w2t [E][D][H] bf16 8.39MB | h [NSLOT][H] bf16 33.6MB
// y [NSLOT][D] fp32 33.6MB (xbf [N][D] bf16 8.4MB ALIASES y: dead before gemm2 writes y)
#define W1T_OFF  0ull
#define W2T_OFF  8388608ull
#define H_OFF    16777216ull
#define Y_OFF    50331648ull
#define XBF_OFF  50331648ull     // alias of Y (xbf consumed by gemm1; y written by gemm2)
#define TOPI_OFF 83886080ull
#define TOPW_OFF 83951616ull
#define SLOT_OFF 84017152ull
#define ROWS_OFF 84082688ull
#define RW_OFF   84148224ull
#define CNT_OFF  84213760ull     // cnt[32] ints; chunk_base[256] ints at CNT_OFF+128

__device__ __forceinline__ unsigned int f2bfu(float f) {
  union { float f; unsigned int i; } v; v.f = f;
  unsigned int u = v.i;
  return (u + 0x7FFFu + ((u >> 16) & 1u)) >> 16;  // RNE, bf16 bits in low 16
}

// ================= 1. weight transpose + downcast, x downcast =================
// blocks [0,1024): w1 fp32 [E][512][1024] -> w1t bf16 [E][1024][512]
// blocks [1024,2048): w2 fp32 [E][1024][512] -> w2t bf16 [E][512][1024]
// blocks [2048,4096): x fp32 [N][512] -> xbf bf16 (elementwise)
__global__ __launch_bounds__(256) void k_transpose(
    const float* __restrict__ w1, const float* __restrict__ w2,
    const float* __restrict__ x,
    unsigned short* __restrict__ w1t, unsigned short* __restrict__ w2t,
    unsigned short* __restrict__ xbf) {
  int b = blockIdx.x;
  int tid = threadIdx.x;
  if (b >= 2048) {                         // x cast: 2048 blocks x 2048 elems
    size_t base = (size_t)(b - 2048) * 2048 + tid * 8;
    float4 a0 = *(const float4*)(x + base);
    float4 a1 = *(const float4*)(x + base + 4);
    uint4 pa;
    pa.x = f2bfu(a0.x) | (f2bfu(a0.y) << 16);
    pa.y = f2bfu(a0.z) | (f2bfu(a0.w) << 16);
    pa.z = f2bfu(a1.x) | (f2bfu(a1.y) << 16);
    pa.w = f2bfu(a1.z) | (f2bfu(a1.w) << 16);
    *(uint4*)(xbf + base) = pa;
    return;
  }
  __shared__ unsigned short tile[64][68];   // +4 pad breaks bank conflicts
  const float* src; unsigned short* dst; int R, C;
  if (b < 1024) { int e = b >> 7; int t = b & 127;
    src = w1 + (size_t)e * 524288; dst = w1t + (size_t)e * 524288; R = 512; C = 1024;
    int tr = t >> 4, tc = t & 15;  // 8 x 16 tiles of 64x64
    src += (size_t)tr * 64 * C + tc * 64; dst += (size_t)tc * 64 * R + tr * 64;
  } else { b -= 1024; int e = b >> 7; int t = b & 127;
    src = w2 + (size_t)e * 524288; dst = w2t + (size_t)e * 524288; R = 1024; C = 512;
    int tr = t >> 3, tc = t & 7;   // 16 x 8 tiles
    src += (size_t)tr * 64 * C + tc * 64; dst += (size_t)tc * 64 * R + tr * 64;
  }
#pragma unroll
  for (int i = 0; i < 4; ++i) {
    int l = i * 256 + tid;
    int r = l >> 4, c4 = (l & 15) << 2;
    float4 v = *(const float4*)(src + (size_t)r * C + c4);
    tile[r][c4 + 0] = (unsigned short)f2bfu(v.x);
    tile[r][c4 + 1] = (unsigned short)f2bfu(v.y);
    tile[r][c4 + 2] = (unsigned short)f2bfu(v.z);
    tile[r][c4 + 3] = (unsigned short)f2bfu(v.w);
  }
  __syncthreads();
#pragma unroll
  for (int i = 0; i < 4; ++i) {
    int l = i * 256 + tid;
    int rr = l >> 4, c4 = (l & 15) << 2;
    ushort4 v;
    v.x = tile[c4 + 0][rr]; v.y = tile[c4 + 1][rr]; v.z = tile[c4 + 2][rr]; v.w = tile[c4 + 3][rr];
    *(ushort4*)(dst + (size_t)rr * R + c4) = v;
  }
}

// ================= 2. router: one wave per token (fp32), NO global atomics =================
__global__ __launch_bounds__(256) void k_router(
    const float* __restrict__ x, const float* __restrict__ gw,
    const float* __restrict__ gb, float* __restrict__ probs_out,
    int2* __restrict__ topi, float2* __restrict__ topw) {
  int wave = threadIdx.x >> 6, lane = threadIdx.x & 63;
  int n = blockIdx.x * 4 + wave;
  const float4* xr = (const float4*)(x + (size_t)n * DIM);
  float4 x0 = xr[lane * 2], x1 = xr[lane * 2 + 1];
  float xf[8] = {x0.x, x0.y, x0.z, x0.w, x1.x, x1.y, x1.z, x1.w};
  float acc[8] = {0.f,0.f,0.f,0.f,0.f,0.f,0.f,0.f};
  const float4* gwr = (const float4*)gw;   // row d = 8 fp32 = two float4
#pragma unroll
  for (int j = 0; j < 8; ++j) {
    int d = lane * 8 + j;
    float4 g0 = gwr[d * 2], g1 = gwr[d * 2 + 1];
    acc[0] += xf[j] * g0.x; acc[1] += xf[j] * g0.y; acc[2] += xf[j] * g0.z; acc[3] += xf[j] * g0.w;
    acc[4] += xf[j] * g1.x; acc[5] += xf[j] * g1.y; acc[6] += xf[j] * g1.z; acc[7] += xf[j] * g1.w;
  }
#pragma unroll
  for (int o = 1; o < 64; o <<= 1)
#pragma unroll
    for (int e = 0; e < 8; ++e) acc[e] += __shfl_xor(acc[e], o, 64);
  float p[8], mx = -1e30f, s = 0.f;
#pragma unroll
  for (int e = 0; e < 8; ++e) { p[e] = acc[e] + gb[e]; mx = fmaxf(mx, p[e]); }
#pragma unroll
  for (int e = 0; e < 8; ++e) { p[e] = __expf(p[e] - mx); s += p[e]; }
  float inv = 1.f / s;
#pragma unroll
  for (int e = 0; e < 8; ++e) p[e] *= inv;
  if (lane < 8) probs_out[(size_t)n * NE + lane] = p[lane];
  if (lane == 0) {
    int i0 = 0; float v0 = p[0];
#pragma unroll
    for (int e = 1; e < 8; ++e) if (p[e] > v0) { v0 = p[e]; i0 = e; }   // first-max (jax tie rule)
    int i1 = -1; float v1 = -1.f;
#pragma unroll
    for (int e = 0; e < 8; ++e) if (e != i0 && p[e] > v1) { v1 = p[e]; i1 = e; }
    float sw = 1.f / (v0 + v1);
    topi[n] = make_int2(i0, i1);
    topw[n] = make_float2(v0 * sw, v1 * sw);
  }
}

// ================= 3. count: histogram + scan + per-chunk bases (1 block) =================
// chunk b (0..31) = tokens [b*256, b*256+256), matching k_assign's blocks.
// Outputs: cnt[0..7]=expert totals, cnt[16..24]=segment offsets (excl scan),
//          chunk_base[b*8+e] = seg_off[e] + sum of chunk hists b'<b.
__global__ __launch_bounds__(1024) void k_count(
    const int2* __restrict__ topi, int* __restrict__ cnt, int* __restrict__ chunk_base) {
  __shared__ int ch[32][8];
  __shared__ int tot[8];
  __shared__ int seg[8];
  int t = threadIdx.x;
  int g = t >> 5;                     // 32 threads per chunk-group
  if (t < 256) ((int*)ch)[t] = 0;
  __syncthreads();
  int c[8] = {0,0,0,0,0,0,0,0};
  int base_tok = t * 8;
#pragma unroll
  for (int i = 0; i < 8; ++i) {
    int2 e = topi[base_tok + i];
#pragma unroll
    for (int k = 0; k < 8; ++k) c[k] += (e.x == k) + (e.y == k);
  }
#pragma unroll
  for (int k = 0; k < 8; ++k) if (c[k]) atomicAdd(&ch[g][k], c[k]);
  __syncthreads();
  if (t < 8) {                        // per-expert exclusive scan over 32 chunks
    int a = 0;
#pragma unroll
    for (int b = 0; b < 32; ++b) { int v = ch[b][t]; ch[b][t] = a; a += v; }
    tot[t] = a; cnt[t] = a;
  }
  __syncthreads();
  if (t == 0) {
    int a = 0;
#pragma unroll
    for (int e = 0; e < 8; ++e) { seg[e] = a; cnt[16 + e] = a; a += tot[e]; }
    cnt[24] = a;                      // = 16384
  }
  __syncthreads();
  if (t < 256) {
    int b = t >> 3, e = t & 7;
    chunk_base[t] = seg[e] + ch[b][e];
  }
}

// ================= 4. slot assignment: LDS atomics only =================
__global__ __launch_bounds__(256) void k_assign(
    const int2* __restrict__ topi, const float2* __restrict__ topw,
    const int* __restrict__ chunk_base,
    int* __restrict__ rows, float* __restrict__ rw, int* __restrict__ slot_of) {
  __shared__ int lcnt[8];
  __shared__ int lbase[8];
  int t = threadIdx.x, b = blockIdx.x;
  if (t < 8) { lcnt[t] = 0; lbase[t] = chunk_base[b * 8 + t]; }
  __syncthreads();
  int n = b * 256 + t;
  int2 ei = topi[n]; float2 wv = topw[n];
  int r0 = atomicAdd(&lcnt[ei.x], 1);
  int r1 = atomicAdd(&lcnt[ei.y], 1);
  int s0 = lbase[ei.x] + r0;
  int s1 = lbase[ei.y] + r1;
  rows[s0] = n; rw[s0] = wv.x; slot_of[2 * n] = s0;
  rows[s1] = n; rw[s1] = wv.y; slot_of[2 * n + 1] = s1;
}

// ================= 5. GEMM1: h = gelu(gather(xbf) @ w1 + b1), h bf16 =================
// grid.x = E*64 (expert, row-tile), grid.y = 8 (HID col-tile). 128x128 tile, BK=64.
__global__ __launch_bounds__(256) void k_gemm1(
    const unsigned short* __restrict__ xbf, const unsigned short* __restrict__ w1t,
    const float* __restrict__ b1, const int* __restrict__ offs,
    const int* __restrict__ rows, unsigned short* __restrict__ h) {
  int e = blockIdx.x >> 6, mt = blockIdx.x & 63;
  int off_e = offs[e], cnt_e = offs[e + 1] - off_e;
  if (mt * 128 >= cnt_e) return;
  int nt = blockIdx.y;
  __shared__ __align__(16) unsigned short As[128 * 64];
  __shared__ __align__(16) unsigned short Bs[128 * 64];
  __shared__ int rows_l[128];
  int tid = threadIdx.x;
  if (tid < 128) {
    int r = mt * 128 + tid;
    rows_l[tid] = rows[off_e + (r < cnt_e ? r : cnt_e - 1)];
  }
  __syncthreads();
  int wave = tid >> 6, lane = tid & 63;
  int wr = wave & 1, wc = wave >> 1;
  f32x4 acc[4][4] = {};
  const unsigned short* bBase = w1t + (size_t)e * HID * DIM;

  for (int k0 = 0; k0 < DIM; k0 += 64) {
#pragma unroll
    for (int j = 0; j < 4; ++j) {
      int l = j * 256 + tid;               // 1024 chunks of 8 bf16
      int r = l >> 3, c = (l & 7) << 3;
      uint4 va = *(const uint4*)(xbf + (size_t)rows_l[r] * DIM + k0 + c);
      uint4 vb = *(const uint4*)(bBase + (size_t)(nt * 128 + r) * DIM + k0 + c);
      *(uint4*)&As[r * 64 + c] = va;
      *(uint4*)&Bs[r * 64 + c] = vb;
    }
    __syncthreads();
#pragma unroll
    for (int kk = 0; kk < 2; ++kk) {
      int ko = kk * 32 + (lane >> 4) * 8;
      short8 a[4], b[4];
#pragma unroll
      for (int m = 0; m < 4; ++m)
        a[m] = *(const short8*)&As[(wr * 64 + m * 16 + (lane & 15)) * 64 + ko];
#pragma unroll
      for (int nb = 0; nb < 4; ++nb)
        b[nb] = *(const short8*)&Bs[(wc * 64 + nb * 16 + (lane & 15)) * 64 + ko];
#pragma unroll
      for (int m = 0; m < 4; ++m)
#pragma unroll
        for (int nb = 0; nb < 4; ++nb)
          acc[m][nb] = __builtin_amdgcn_mfma_f32_16x16x32_bf16(a[m], b[nb], acc[m][nb], 0, 0, 0);
    }
    __syncthreads();
  }
  int rq = (lane >> 4) * 4;
#pragma unroll
  for (int m = 0; m < 4; ++m) {
    int rl = wr * 64 + m * 16 + rq;
#pragma unroll
    for (int nb = 0; nb < 4; ++nb) {
      int col = nt * 128 + wc * 64 + nb * 16 + (lane & 15);
      float bias = b1[e * HID + col];
#pragma unroll
      for (int i = 0; i < 4; ++i) {
        int r = mt * 128 + rl + i;
        if (r < cnt_e) {
          float v = acc[m][nb][i] + bias;
          float g = 0.5f * v * (1.0f + erff(v * 0.70710678118654752f));   // exact GELU
          h[(size_t)(off_e + r) * HID + col] = (unsigned short)f2bfu(g);
        }
      }
    }
  }
}

// ================= 6. GEMM2: y = (h @ w2 + b2) * weight, y fp32 =================
// grid.x = E*64, grid.y = 4 (DIM col-tile). K = HID = 1024.
__global__ __launch_bounds__(256) void k_gemm2(
    const unsigned short* __restrict__ h, const unsigned short* __restrict__ w2t,
    const float* __restrict__ b2, const int* __restrict__ offs,
    const float* __restrict__ rw, float* __restrict__ y) {
  int e = blockIdx.x >> 6, mt = blockIdx.x & 63;
  int off_e = offs[e], cnt_e = offs[e + 1] - off_e;
  if (mt * 128 >= cnt_e) return;
  int nt = blockIdx.y;
  __shared__ __align__(16) unsigned short As[128 * 64];
  __shared__ __align__(16) unsigned short Bs[128 * 64];
  int tid = threadIdx.x;
  int wave = tid >> 6, lane = tid & 63;
  int wr = wave & 1, wc = wave >> 1;
  f32x4 acc[4][4] = {};
  const unsigned short* aBase = h + (size_t)off_e * HID;
  const unsigned short* bBase = w2t + (size_t)e * DIM * HID;
  int rmax = cnt_e - 1;

  for (int k0 = 0; k0 < HID; k0 += 64) {
#pragma unroll
    for (int j = 0; j < 4; ++j) {
      int l = j * 256 + tid;
      int r = l >> 3, c = (l & 7) << 3;
      int ra = mt * 128 + r; if (ra > rmax) ra = rmax;
      uint4 va = *(const uint4*)(aBase + (size_t)ra * HID + k0 + c);
      uint4 vb = *(const uint4*)(bBase + (size_t)(nt * 128 + r) * HID + k0 + c);
      *(uint4*)&As[r * 64 + c] = va;
      *(uint4*)&Bs[r * 64 + c] = vb;
    }
    __syncthreads();
#pragma unroll
    for (int kk = 0; kk < 2; ++kk) {
      int ko = kk * 32 + (lane >> 4) * 8;
      short8 a[4], b[4];
#pragma unroll
      for (int m = 0; m < 4; ++m)
        a[m] = *(const short8*)&As[(wr * 64 + m * 16 + (lane & 15)) * 64 + ko];
#pragma unroll
      for (int nb = 0; nb < 4; ++nb)
        b[nb] = *(const short8*)&Bs[(wc * 64 + nb * 16 + (lane & 15)) * 64 + ko];
#pragma unroll
      for (int m = 0; m < 4; ++m)
#pragma unroll
        for (int nb = 0; nb < 4; ++nb)
          acc[m][nb] = __builtin_amdgcn_mfma_f32_16x16x32_bf16(a[m], b[nb], acc[m][nb], 0, 0, 0);
    }
    __syncthreads();
  }
  int rq = (lane >> 4) * 4;
#pragma unroll
  for (int m = 0; m < 4; ++m) {
    int rl = wr * 64 + m * 16 + rq;
#pragma unroll
    for (int nb = 0; nb < 4; ++nb) {
      int col = nt * 128 + wc * 64 + nb * 16 + (lane & 15);
      float bias = b2[e * DIM + col];
#pragma unroll
      for (int i = 0; i < 4; ++i) {
        int r = mt * 128 + rl + i;
        if (r < cnt_e) {
          float w = rw[off_e + r];
          y[(size_t)(off_e + r) * DIM + col] = (acc[m][nb][i] + bias) * w;
        }
      }
    }
  }
}

// ================= 7. combine: out[n] = y[slot0] + y[slot1] (fp32) =================
__global__ __launch_bounds__(256) void k_combine(
    const float* __restrict__ y, const int* __restrict__ slot_of,
    float* __restrict__ out) {
  int t = blockIdx.x * 256 + threadIdx.x;   // N_TOK*128 threads, 4 fp32 each
  int n = t >> 7, c = (t & 127) << 2;
  int s0 = slot_of[2 * n], s1 = slot_of[2 * n + 1];
  float4 u0 = *(const float4*)(y + (size_t)s0 * DIM + c);
  float4 u1 = *(const float4*)(y + (size_t)s1 * DIM + c);
  float4 o;
  o.x = u0.x + u1.x; o.y = u0.y + u1.y; o.z = u0.z + u1.z; o.w = u0.w + u1.w;
  *(float4*)(out + (size_t)n * DIM + c) = o;
}

// ================= launch =================
extern "C" void kernel_launch(void* const* d_in, const int* in_sizes, int n_in,
                              void* d_out, int out_size, void* d_ws, size_t ws_size,
                              hipStream_t stream) {
  const float* x  = (const float*)d_in[0];
  const float* gw = (const float*)d_in[1];
  const float* gb = (const float*)d_in[2];
  const float* w1 = (const float*)d_in[3];
  const float* b1 = (const float*)d_in[4];
  const float* w2 = (const float*)d_in[5];
  const float* b2 = (const float*)d_in[6];
  float* out = (float*)d_out;
  char* ws = (char*)d_ws;

  unsigned short* w1t = (unsigned short*)(ws + W1T_OFF);
  unsigned short* w2t = (unsigned short*)(ws + W2T_OFF);
  unsigned short* h   = (unsigned short*)(ws + H_OFF);
  float*          y   = (float*)(ws + Y_OFF);
  unsigned short* xbf = (unsigned short*)(ws + XBF_OFF);   // aliases y (dead before gemm2)
  int2*   topi    = (int2*)(ws + TOPI_OFF);
  float2* topw    = (float2*)(ws + TOPW_OFF);
  int*    slot_of = (int*)(ws + SLOT_OFF);
  int*    rows    = (int*)(ws + ROWS_OFF);
  float*  rw      = (float*)(ws + RW_OFF);
  int*    cnt     = (int*)(ws + CNT_OFF);
  int*    chunk_base = cnt + 32;
  float*  probs   = out + (size_t)N_TOK * DIM;   // outputs: [out | probs]

  k_transpose<<<dim3(4096), dim3(256), 0, stream>>>(w1, w2, x, w1t, w2t, xbf);
  k_router   <<<dim3(2048), dim3(256), 0, stream>>>(x, gw, gb, probs, topi, topw);
  k_count    <<<dim3(1),    dim3(1024), 0, stream>>>(topi, cnt, chunk_base);
  k_assign   <<<dim3(32),   dim3(256), 0, stream>>>(topi, topw, chunk_base, rows, rw, slot_of);
  k_gemm1    <<<dim3(512, 8), dim3(256), 0, stream>>>(xbf, w1t, b1, cnt + 16, rows, h);
  k_gemm2    <<<dim3(512, 4), dim3(256), 0, stream>>>(h, w2t, b2, cnt + 16, rw, y);
  k_combine  <<<dim3(4096), dim3(256), 0, stream>>>(y, slot_of, out);
}

// Round 5
// 240.045 us; speedup vs baseline: 2.3557x; 1.2593x over previous
//
#include <hip/hip_runtime.h>
#include <stdint.h>

// ---------------- problem constants ----------------
#define N_TOK 8192      // B*S = 4*2048
#define DIM   512       // D
#define HID   1024      // H
#define NE    8         // experts
#define NSLOT 16384     // N_TOK * K (K=2)
#define MAXSLOT 17408   // padded slots (<= 135*128 = 17280, rounded up)

typedef __attribute__((ext_vector_type(8))) short short8;   // 8 x bf16 (4 VGPRs)
typedef __attribute__((ext_vector_type(4))) float f32x4;    // MFMA C/D frag

// ---------------- workspace layout (bytes) ----------------
// w1t [E][H][D] bf16 | w2t [E][D][H] bf16 | h [MAXSLOT][H] bf16 | y [MAXSLOT][D] bf16
// xbf [N][D] bf16 aliases y (dead before gemm2 writes y)
#define W1T_OFF  0ull
#define W2T_OFF  8388608ull
#define H_OFF    16777216ull          // 17408*1024*2 = 35651584
#define Y_OFF    52428800ull          // 17408*512*2  = 17825792
#define XBF_OFF  52428800ull          // alias of Y
#define TOPI_OFF 70254592ull
#define TOPW_OFF 70320128ull
#define SLOT_OFF 70385664ull
#define ROWS_OFF 70451200ull          // 17408*4
#define RW_OFF   70520832ull          // 17408*4
#define CNT_OFF  70590464ull          // meta ints; chunk_base at +256B

__device__ __forceinline__ unsigned int f2bfu(float f) {
  union { float f; unsigned int i; } v; v.f = f;
  unsigned int u = v.i;
  return (u + 0x7FFFu + ((u >> 16) & 1u)) >> 16;  // RNE, bf16 bits in low 16
}
__device__ __forceinline__ float bf2f(unsigned int u) {
  union { unsigned int i; float f; } v; v.i = (u & 0xFFFFu) << 16; return v.f;
}
// async global->LDS, 16B/lane. LDS dest = wave-uniform base + lane*16.
__device__ __forceinline__ void async16(void* lds, const void* g) {
  __builtin_amdgcn_global_load_lds(
      (const __attribute__((address_space(1))) unsigned int*)g,
      (__attribute__((address_space(3))) unsigned int*)lds, 16, 0, 0);
}

// ================= 1. weight transpose + downcast =================
// blocks [0,1024): w1 fp32 [E][512][1024] -> w1t bf16 [E][1024][512]
// blocks [1024,2048): w2 fp32 [E][1024][512] -> w2t bf16 [E][512][1024]
__global__ __launch_bounds__(256) void k_transpose(
    const float* __restrict__ w1, const float* __restrict__ w2,
    unsigned short* __restrict__ w1t, unsigned short* __restrict__ w2t) {
  __shared__ unsigned short tile[64][68];   // +4 pad breaks bank conflicts
  int b = blockIdx.x, tid = threadIdx.x;
  const float* src; unsigned short* dst; int R, C;
  if (b < 1024) { int e = b >> 7; int t = b & 127;
    src = w1 + (size_t)e * 524288; dst = w1t + (size_t)e * 524288; R = 512; C = 1024;
    int tr = t >> 4, tc = t & 15;  // 8 x 16 tiles of 64x64
    src += (size_t)tr * 64 * C + tc * 64; dst += (size_t)tc * 64 * R + tr * 64;
  } else { b -= 1024; int e = b >> 7; int t = b & 127;
    src = w2 + (size_t)e * 524288; dst = w2t + (size_t)e * 524288; R = 1024; C = 512;
    int tr = t >> 3, tc = t & 7;   // 16 x 8 tiles
    src += (size_t)tr * 64 * C + tc * 64; dst += (size_t)tc * 64 * R + tr * 64;
  }
#pragma unroll
  for (int i = 0; i < 4; ++i) {
    int l = i * 256 + tid;
    int r = l >> 4, c4 = (l & 15) << 2;
    float4 v = *(const float4*)(src + (size_t)r * C + c4);
    tile[r][c4 + 0] = (unsigned short)f2bfu(v.x);
    tile[r][c4 + 1] = (unsigned short)f2bfu(v.y);
    tile[r][c4 + 2] = (unsigned short)f2bfu(v.z);
    tile[r][c4 + 3] = (unsigned short)f2bfu(v.w);
  }
  __syncthreads();
#pragma unroll
  for (int i = 0; i < 4; ++i) {
    int l = i * 256 + tid;
    int rr = l >> 4, c4 = (l & 15) << 2;
    ushort4 v;
    v.x = tile[c4 + 0][rr]; v.y = tile[c4 + 1][rr]; v.z = tile[c4 + 2][rr]; v.w = tile[c4 + 3][rr];
    *(ushort4*)(dst + (size_t)rr * R + c4) = v;
  }
}

// ================= 2. router: one wave per token; also emits xbf =================
__global__ __launch_bounds__(256) void k_router(
    const float* __restrict__ x, const float* __restrict__ gw,
    const float* __restrict__ gb, float* __restrict__ probs_out,
    int2* __restrict__ topi, float2* __restrict__ topw,
    unsigned short* __restrict__ xbf) {
  int wave = threadIdx.x >> 6, lane = threadIdx.x & 63;
  int n = blockIdx.x * 4 + wave;
  const float4* xr = (const float4*)(x + (size_t)n * DIM);
  float4 x0 = xr[lane * 2], x1 = xr[lane * 2 + 1];
  float xf[8] = {x0.x, x0.y, x0.z, x0.w, x1.x, x1.y, x1.z, x1.w};
  uint4 pa;                                  // x -> bf16 while it's in registers
  pa.x = f2bfu(xf[0]) | (f2bfu(xf[1]) << 16);
  pa.y = f2bfu(xf[2]) | (f2bfu(xf[3]) << 16);
  pa.z = f2bfu(xf[4]) | (f2bfu(xf[5]) << 16);
  pa.w = f2bfu(xf[6]) | (f2bfu(xf[7]) << 16);
  *(uint4*)(xbf + (size_t)n * DIM + lane * 8) = pa;
  float acc[8] = {0.f,0.f,0.f,0.f,0.f,0.f,0.f,0.f};
  const float4* gwr = (const float4*)gw;
#pragma unroll
  for (int j = 0; j < 8; ++j) {
    int d = lane * 8 + j;
    float4 g0 = gwr[d * 2], g1 = gwr[d * 2 + 1];
    acc[0] += xf[j] * g0.x; acc[1] += xf[j] * g0.y; acc[2] += xf[j] * g0.z; acc[3] += xf[j] * g0.w;
    acc[4] += xf[j] * g1.x; acc[5] += xf[j] * g1.y; acc[6] += xf[j] * g1.z; acc[7] += xf[j] * g1.w;
  }
#pragma unroll
  for (int o = 1; o < 64; o <<= 1)
#pragma unroll
    for (int e = 0; e < 8; ++e) acc[e] += __shfl_xor(acc[e], o, 64);
  float p[8], mx = -1e30f, s = 0.f;
#pragma unroll
  for (int e = 0; e < 8; ++e) { p[e] = acc[e] + gb[e]; mx = fmaxf(mx, p[e]); }
#pragma unroll
  for (int e = 0; e < 8; ++e) { p[e] = __expf(p[e] - mx); s += p[e]; }
  float inv = 1.f / s;
#pragma unroll
  for (int e = 0; e < 8; ++e) p[e] *= inv;
  if (lane < 8) probs_out[(size_t)n * NE + lane] = p[lane];
  if (lane == 0) {
    int i0 = 0; float v0 = p[0];
#pragma unroll
    for (int e = 1; e < 8; ++e) if (p[e] > v0) { v0 = p[e]; i0 = e; }   // first-max (jax tie rule)
    int i1 = -1; float v1 = -1.f;
#pragma unroll
    for (int e = 0; e < 8; ++e) if (e != i0 && p[e] > v1) { v1 = p[e]; i1 = e; }
    float sw = 1.f / (v0 + v1);
    topi[n] = make_int2(i0, i1);
    topw[n] = make_float2(v0 * sw, v1 * sw);
  }
}

// ================= 3. count: histogram + padded scan + tile map + pad fill =================
// meta[0..7]=totals, meta[16..24]=poff (128-padded seg offsets), meta[32..40]=tile_start,
// chunk_base[b*8+e] = poff[e] + prefix of chunks b'<b. Pad slots get rows=0, rw=0.
__global__ __launch_bounds__(1024) void k_count(
    const int2* __restrict__ topi, int* __restrict__ meta, int* __restrict__ chunk_base,
    int* __restrict__ rows, float* __restrict__ rw) {
  __shared__ int ch[32][8];
  __shared__ int tot[8], poff_s[9], tiles_s[8];
  int t = threadIdx.x;
  int g = t >> 5;
  if (t < 256) ((int*)ch)[t] = 0;
  __syncthreads();
  int c[8] = {0,0,0,0,0,0,0,0};
  int base_tok = t * 8;
#pragma unroll
  for (int i = 0; i < 8; ++i) {
    int2 e = topi[base_tok + i];
#pragma unroll
    for (int k = 0; k < 8; ++k) c[k] += (e.x == k) + (e.y == k);
  }
#pragma unroll
  for (int k = 0; k < 8; ++k) if (c[k]) atomicAdd(&ch[g][k], c[k]);
  __syncthreads();
  if (t < 8) {                        // per-expert exclusive scan over 32 chunks
    int a = 0;
#pragma unroll
    for (int b = 0; b < 32; ++b) { int v = ch[b][t]; ch[b][t] = a; a += v; }
    tot[t] = a; meta[t] = a;
  }
  __syncthreads();
  if (t == 0) {
    int a = 0, ts = 0;
#pragma unroll
    for (int e = 0; e < 8; ++e) {
      int tiles = (tot[e] + 127) >> 7;
      poff_s[e] = a; tiles_s[e] = tiles;
      meta[16 + e] = a; meta[32 + e] = ts;
      a += tiles << 7; ts += tiles;
    }
    poff_s[8] = a; meta[24] = a; meta[40] = ts;
  }
  __syncthreads();
  if (t < 256) {
    int b = t >> 3, e = t & 7;
    chunk_base[t] = poff_s[e] + ch[b][e];
  }
  // pad fill: slots [poff[e]+tot[e], poff[e]+tiles*128)
#pragma unroll
  for (int e = 0; e < 8; ++e) {
    int padn = (tiles_s[e] << 7) - tot[e];
    if (t < padn) {
      int s = poff_s[e] + tot[e] + t;
      rows[s] = 0; rw[s] = 0.f;
    }
  }
}

// ================= 4. slot assignment: LDS atomics only =================
__global__ __launch_bounds__(256) void k_assign(
    const int2* __restrict__ topi, const float2* __restrict__ topw,
    const int* __restrict__ chunk_base,
    int* __restrict__ rows, float* __restrict__ rw, int* __restrict__ slot_of) {
  __shared__ int lcnt[8];
  __shared__ int lbase[8];
  int t = threadIdx.x, b = blockIdx.x;
  if (t < 8) { lcnt[t] = 0; lbase[t] = chunk_base[b * 8 + t]; }
  __syncthreads();
  int n = b * 256 + t;
  int2 ei = topi[n]; float2 wv = topw[n];
  int r0 = atomicAdd(&lcnt[ei.x], 1);
  int r1 = atomicAdd(&lcnt[ei.y], 1);
  int s0 = lbase[ei.x] + r0;
  int s1 = lbase[ei.y] + r1;
  rows[s0] = n; rw[s0] = wv.x; slot_of[2 * n] = s0;
  rows[s1] = n; rw[s1] = wv.y; slot_of[2 * n + 1] = s1;
}

// ================= 5. GEMM1: h = gelu(gather(xbf) @ w1 + b1), h bf16 =================
// grid (136, 8). Tile 128x128, BK=64. Async global->LDS, XOR-swizzled LDS layout:
// chunk (r, c) [c = 8-elem column 0..7] lives at LDS slot r*8 + (c ^ (r&7)).
__global__ __launch_bounds__(256) void k_gemm1(
    const unsigned short* __restrict__ xbf, const unsigned short* __restrict__ w1t,
    const float* __restrict__ b1, const int* __restrict__ meta,
    const int* __restrict__ rows, unsigned short* __restrict__ h) {
  int t = blockIdx.x;
  if (t >= meta[40]) return;
  int e = 0;
#pragma unroll
  for (int i = 1; i < 8; ++i) if (t >= meta[32 + i]) e = i;
  int mt = t - meta[32 + e];
  int row0 = meta[16 + e] + (mt << 7);     // padded slot base; all 128 rows valid
  int nt = blockIdx.y;
  __shared__ __align__(16) unsigned short As[128 * 64];
  __shared__ __align__(16) unsigned short Bs[128 * 64];
  __shared__ int rows_l[128];
  int tid = threadIdx.x;
  if (tid < 128) rows_l[tid] = rows[row0 + tid];
  __syncthreads();
  int wave = tid >> 6, lane = tid & 63;
  int wr = wave & 1, wc = wave >> 1;
  f32x4 acc[4][4] = {};
  const unsigned short* bBase = w1t + (size_t)e * HID * DIM + (size_t)(nt * 128) * DIM;

  for (int k0 = 0; k0 < DIM; k0 += 64) {
#pragma unroll
    for (int j = 0; j < 4; ++j) {
      int s = j * 256 + tid;               // LDS slot; lane's slot = wavebase + lane
      int r = s >> 3;
      int cg = ((s & 7) ^ (r & 7)) << 3;   // inverse swizzle -> global element col
      async16(&As[(j * 256 + wave * 64) * 8], xbf + (size_t)rows_l[r] * DIM + k0 + cg);
      async16(&Bs[(j * 256 + wave * 64) * 8], bBase + (size_t)r * DIM + k0 + cg);
    }
    __syncthreads();   // drains vmcnt -> LDS valid
#pragma unroll
    for (int kk = 0; kk < 2; ++kk) {
      int ca = kk * 4 + (lane >> 4);       // chunk col for this quad
      short8 a[4], b[4];
#pragma unroll
      for (int m = 0; m < 4; ++m) {
        int ra = wr * 64 + m * 16 + (lane & 15);
        a[m] = *(const short8*)&As[(ra * 8 + (ca ^ (ra & 7))) * 8];
      }
#pragma unroll
      for (int nb = 0; nb < 4; ++nb) {
        int rb = wc * 64 + nb * 16 + (lane & 15);
        b[nb] = *(const short8*)&Bs[(rb * 8 + (ca ^ (rb & 7))) * 8];
      }
#pragma unroll
      for (int m = 0; m < 4; ++m)
#pragma unroll
        for (int nb = 0; nb < 4; ++nb)
          acc[m][nb] = __builtin_amdgcn_mfma_f32_16x16x32_bf16(a[m], b[nb], acc[m][nb], 0, 0, 0);
    }
    __syncthreads();
  }
  int rq = (lane >> 4) * 4;
#pragma unroll
  for (int m = 0; m < 4; ++m) {
    int rl = wr * 64 + m * 16 + rq;
#pragma unroll
    for (int nb = 0; nb < 4; ++nb) {
      int col = nt * 128 + wc * 64 + nb * 16 + (lane & 15);
      float bias = b1[e * HID + col];
#pragma unroll
      for (int i = 0; i < 4; ++i) {
        float v = acc[m][nb][i] + bias;
        float g = 0.5f * v * (1.0f + erff(v * 0.70710678118654752f));   // exact GELU
        h[(size_t)(row0 + rl + i) * HID + col] = (unsigned short)f2bfu(g);
      }
    }
  }
}

// ================= 6. GEMM2: y = (h @ w2 + b2) * weight, y bf16 =================
// grid (136, 4). K = HID = 1024. Same swizzled async staging.
__global__ __launch_bounds__(256) void k_gemm2(
    const unsigned short* __restrict__ h, const unsigned short* __restrict__ w2t,
    const float* __restrict__ b2, const int* __restrict__ meta,
    const float* __restrict__ rw, unsigned short* __restrict__ y) {
  int t = blockIdx.x;
  if (t >= meta[40]) return;
  int e = 0;
#pragma unroll
  for (int i = 1; i < 8; ++i) if (t >= meta[32 + i]) e = i;
  int mt = t - meta[32 + e];
  int row0 = meta[16 + e] + (mt << 7);
  int nt = blockIdx.y;
  __shared__ __align__(16) unsigned short As[128 * 64];
  __shared__ __align__(16) unsigned short Bs[128 * 64];
  int tid = threadIdx.x;
  int wave = tid >> 6, lane = tid & 63;
  int wr = wave & 1, wc = wave >> 1;
  f32x4 acc[4][4] = {};
  const unsigned short* aBase = h + (size_t)row0 * HID;
  const unsigned short* bBase = w2t + (size_t)e * DIM * HID + (size_t)(nt * 128) * HID;

  for (int k0 = 0; k0 < HID; k0 += 64) {
#pragma unroll
    for (int j = 0; j < 4; ++j) {
      int s = j * 256 + tid;
      int r = s >> 3;
      int cg = ((s & 7) ^ (r & 7)) << 3;
      async16(&As[(j * 256 + wave * 64) * 8], aBase + (size_t)r * HID + k0 + cg);
      async16(&Bs[(j * 256 + wave * 64) * 8], bBase + (size_t)r * HID + k0 + cg);
    }
    __syncthreads();
#pragma unroll
    for (int kk = 0; kk < 2; ++kk) {
      int ca = kk * 4 + (lane >> 4);
      short8 a[4], b[4];
#pragma unroll
      for (int m = 0; m < 4; ++m) {
        int ra = wr * 64 + m * 16 + (lane & 15);
        a[m] = *(const short8*)&As[(ra * 8 + (ca ^ (ra & 7))) * 8];
      }
#pragma unroll
      for (int nb = 0; nb < 4; ++nb) {
        int rb = wc * 64 + nb * 16 + (lane & 15);
        b[nb] = *(const short8*)&Bs[(rb * 8 + (ca ^ (rb & 7))) * 8];
      }
#pragma unroll
      for (int m = 0; m < 4; ++m)
#pragma unroll
        for (int nb = 0; nb < 4; ++nb)
          acc[m][nb] = __builtin_amdgcn_mfma_f32_16x16x32_bf16(a[m], b[nb], acc[m][nb], 0, 0, 0);
    }
    __syncthreads();
  }
  int rq = (lane >> 4) * 4;
#pragma unroll
  for (int m = 0; m < 4; ++m) {
    int rl = wr * 64 + m * 16 + rq;
#pragma unroll
    for (int nb = 0; nb < 4; ++nb) {
      int col = nt * 128 + wc * 64 + nb * 16 + (lane & 15);
      float bias = b2[e * DIM + col];
#pragma unroll
      for (int i = 0; i < 4; ++i) {
        int rsl = row0 + rl + i;
        float w = rw[rsl];
        y[(size_t)rsl * DIM + col] = (unsigned short)f2bfu((acc[m][nb][i] + bias) * w);
      }
    }
  }
}

// ================= 7. combine: out[n] = y[slot0] + y[slot1] (bf16 -> fp32) =================
__global__ __launch_bounds__(256) void k_combine(
    const unsigned short* __restrict__ y, const int* __restrict__ slot_of,
    float* __restrict__ out) {
  int t = blockIdx.x * 256 + threadIdx.x;   // N_TOK*64 threads, 8 elems each
  int n = t >> 6, c = (t & 63) << 3;
  int s0 = slot_of[2 * n], s1 = slot_of[2 * n + 1];
  uint4 u0 = *(const uint4*)(y + (size_t)s0 * DIM + c);
  uint4 u1 = *(const uint4*)(y + (size_t)s1 * DIM + c);
  float4 o0, o1;
  o0.x = bf2f(u0.x) + bf2f(u1.x); o0.y = bf2f(u0.x >> 16) + bf2f(u1.x >> 16);
  o0.z = bf2f(u0.y) + bf2f(u1.y); o0.w = bf2f(u0.y >> 16) + bf2f(u1.y >> 16);
  o1.x = bf2f(u0.z) + bf2f(u1.z); o1.y = bf2f(u0.z >> 16) + bf2f(u1.z >> 16);
  o1.z = bf2f(u0.w) + bf2f(u1.w); o1.w = bf2f(u0.w >> 16) + bf2f(u1.w >> 16);
  *(float4*)(out + (size_t)n * DIM + c) = o0;
  *(float4*)(out + (size_t)n * DIM + c + 4) = o1;
}

// ================= launch =================
extern "C" void kernel_launch(void* const* d_in, const int* in_sizes, int n_in,
                              void* d_out, int out_size, void* d_ws, size_t ws_size,
                              hipStream_t stream) {
  const float* x  = (const float*)d_in[0];
  const float* gw = (const float*)d_in[1];
  const float* gb = (const float*)d_in[2];
  const float* w1 = (const float*)d_in[3];
  const float* b1 = (const float*)d_in[4];
  const float* w2 = (const float*)d_in[5];
  const float* b2 = (const float*)d_in[6];
  float* out = (float*)d_out;
  char* ws = (char*)d_ws;

  unsigned short* w1t = (unsigned short*)(ws + W1T_OFF);
  unsigned short* w2t = (unsigned short*)(ws + W2T_OFF);
  unsigned short* h   = (unsigned short*)(ws + H_OFF);
  unsigned short* y   = (unsigned short*)(ws + Y_OFF);
  unsigned short* xbf = (unsigned short*)(ws + XBF_OFF);   // aliases y
  int2*   topi    = (int2*)(ws + TOPI_OFF);
  float2* topw    = (float2*)(ws + TOPW_OFF);
  int*    slot_of = (int*)(ws + SLOT_OFF);
  int*    rows    = (int*)(ws + ROWS_OFF);
  float*  rw      = (float*)(ws + RW_OFF);
  int*    meta    = (int*)(ws + CNT_OFF);
  int*    chunk_base = meta + 64;
  float*  probs   = out + (size_t)N_TOK * DIM;   // outputs: [out | probs]

  k_transpose<<<dim3(2048), dim3(256), 0, stream>>>(w1, w2, w1t, w2t);
  k_router   <<<dim3(2048), dim3(256), 0, stream>>>(x, gw, gb, probs, topi, topw, xbf);
  k_count    <<<dim3(1),    dim3(1024), 0, stream>>>(topi, meta, chunk_base, rows, rw);
  k_assign   <<<dim3(32),   dim3(256), 0, stream>>>(topi, topw, chunk_base, rows, rw, slot_of);
  k_gemm1    <<<dim3(136, 8), dim3(256), 0, stream>>>(xbf, w1t, b1, meta, rows, h);
  k_gemm2    <<<dim3(136, 4), dim3(256), 0, stream>>>(h, w2t, b2, meta, rw, y);
  k_combine  <<<dim3(2048), dim3(256), 0, stream>>>(y, slot_of, out);
}

// Round 6
// 214.329 us; speedup vs baseline: 2.6383x; 1.1200x over previous
//
#include <hip/hip_runtime.h>
#include <stdint.h>

// ---------------- problem constants ----------------
#define N_TOK 8192      // B*S = 4*2048
#define DIM   512       // D
#define HID   1024      // H
#define NE    8         // experts
#define NSLOT 16384     // N_TOK * K (K=2)
#define MAXSLOT 17408   // padded slots (<= 136*128)

typedef __attribute__((ext_vector_type(8))) short short8;   // 8 x bf16 (4 VGPRs)
typedef __attribute__((ext_vector_type(4))) float f32x4;    // MFMA C/D frag

// ---------------- workspace layout (bytes) ----------------
#define W1T_OFF  0ull
#define W2T_OFF  8388608ull
#define H_OFF    16777216ull          // 17408*1024*2 = 35651584
#define Y_OFF    52428800ull          // 17408*512*2  = 17825792
#define XBF_OFF  52428800ull          // alias of Y (xbf dead before gemm2 writes y)
#define TOPI_OFF 70254592ull
#define TOPW_OFF 70320128ull
#define SLOT_OFF 70385664ull
#define ROWS_OFF 70451200ull
#define RW_OFF   70520832ull
#define CNT_OFF  70590464ull

__device__ __forceinline__ unsigned int f2bfu(float f) {
  union { float f; unsigned int i; } v; v.f = f;
  unsigned int u = v.i;
  return (u + 0x7FFFu + ((u >> 16) & 1u)) >> 16;  // RNE, bf16 bits in low 16
}
__device__ __forceinline__ float bf2f(unsigned int u) {
  union { unsigned int i; float f; } v; v.i = (u & 0xFFFFu) << 16; return v.f;
}
// fast GELU: x*sigmoid(1.5957691*x*(1+0.044715*x^2)); max |err| vs erf-GELU ~3e-4
__device__ __forceinline__ float gelu_f(float x) {
  float x2 = x * x;
  float u = x * (1.59576912f + 0.07135481f * x2);
  float ez = __expf(-u);
  return x * __builtin_amdgcn_rcpf(1.0f + ez);
}
// async global->LDS, 16B/lane. LDS dest = wave-uniform base + lane*16.
__device__ __forceinline__ void async16(void* lds, const void* g) {
  __builtin_amdgcn_global_load_lds(
      (const __attribute__((address_space(1))) unsigned int*)g,
      (__attribute__((address_space(3))) unsigned int*)lds, 16, 0, 0);
}

// ================= 1. weight transpose + downcast =================
__global__ __launch_bounds__(256) void k_transpose(
    const float* __restrict__ w1, const float* __restrict__ w2,
    unsigned short* __restrict__ w1t, unsigned short* __restrict__ w2t) {
  __shared__ unsigned short tile[64][68];   // +4 pad breaks bank conflicts
  int b = blockIdx.x, tid = threadIdx.x;
  const float* src; unsigned short* dst; int R, C;
  if (b < 1024) { int e = b >> 7; int t = b & 127;
    src = w1 + (size_t)e * 524288; dst = w1t + (size_t)e * 524288; R = 512; C = 1024;
    int tr = t >> 4, tc = t & 15;  // 8 x 16 tiles of 64x64
    src += (size_t)tr * 64 * C + tc * 64; dst += (size_t)tc * 64 * R + tr * 64;
  } else { b -= 1024; int e = b >> 7; int t = b & 127;
    src = w2 + (size_t)e * 524288; dst = w2t + (size_t)e * 524288; R = 1024; C = 512;
    int tr = t >> 3, tc = t & 7;   // 16 x 8 tiles
    src += (size_t)tr * 64 * C + tc * 64; dst += (size_t)tc * 64 * R + tr * 64;
  }
#pragma unroll
  for (int i = 0; i < 4; ++i) {
    int l = i * 256 + tid;
    int r = l >> 4, c4 = (l & 15) << 2;
    float4 v = *(const float4*)(src + (size_t)r * C + c4);
    tile[r][c4 + 0] = (unsigned short)f2bfu(v.x);
    tile[r][c4 + 1] = (unsigned short)f2bfu(v.y);
    tile[r][c4 + 2] = (unsigned short)f2bfu(v.z);
    tile[r][c4 + 3] = (unsigned short)f2bfu(v.w);
  }
  __syncthreads();
#pragma unroll
  for (int i = 0; i < 4; ++i) {
    int l = i * 256 + tid;
    int rr = l >> 4, c4 = (l & 15) << 2;
    ushort4 v;
    v.x = tile[c4 + 0][rr]; v.y = tile[c4 + 1][rr]; v.z = tile[c4 + 2][rr]; v.w = tile[c4 + 3][rr];
    *(ushort4*)(dst + (size_t)rr * R + c4) = v;
  }
}

// ================= 2. router: one wave per token; also emits xbf =================
__global__ __launch_bounds__(256) void k_router(
    const float* __restrict__ x, const float* __restrict__ gw,
    const float* __restrict__ gb, float* __restrict__ probs_out,
    int2* __restrict__ topi, float2* __restrict__ topw,
    unsigned short* __restrict__ xbf) {
  int wave = threadIdx.x >> 6, lane = threadIdx.x & 63;
  int n = blockIdx.x * 4 + wave;
  const float4* xr = (const float4*)(x + (size_t)n * DIM);
  float4 x0 = xr[lane * 2], x1 = xr[lane * 2 + 1];
  float xf[8] = {x0.x, x0.y, x0.z, x0.w, x1.x, x1.y, x1.z, x1.w};
  uint4 pa;
  pa.x = f2bfu(xf[0]) | (f2bfu(xf[1]) << 16);
  pa.y = f2bfu(xf[2]) | (f2bfu(xf[3]) << 16);
  pa.z = f2bfu(xf[4]) | (f2bfu(xf[5]) << 16);
  pa.w = f2bfu(xf[6]) | (f2bfu(xf[7]) << 16);
  *(uint4*)(xbf + (size_t)n * DIM + lane * 8) = pa;
  float acc[8] = {0.f,0.f,0.f,0.f,0.f,0.f,0.f,0.f};
  const float4* gwr = (const float4*)gw;
#pragma unroll
  for (int j = 0; j < 8; ++j) {
    int d = lane * 8 + j;
    float4 g0 = gwr[d * 2], g1 = gwr[d * 2 + 1];
    acc[0] += xf[j] * g0.x; acc[1] += xf[j] * g0.y; acc[2] += xf[j] * g0.z; acc[3] += xf[j] * g0.w;
    acc[4] += xf[j] * g1.x; acc[5] += xf[j] * g1.y; acc[6] += xf[j] * g1.z; acc[7] += xf[j] * g1.w;
  }
#pragma unroll
  for (int o = 1; o < 64; o <<= 1)
#pragma unroll
    for (int e = 0; e < 8; ++e) acc[e] += __shfl_xor(acc[e], o, 64);
  float p[8], mx = -1e30f, s = 0.f;
#pragma unroll
  for (int e = 0; e < 8; ++e) { p[e] = acc[e] + gb[e]; mx = fmaxf(mx, p[e]); }
#pragma unroll
  for (int e = 0; e < 8; ++e) { p[e] = __expf(p[e] - mx); s += p[e]; }
  float inv = 1.f / s;
#pragma unroll
  for (int e = 0; e < 8; ++e) p[e] *= inv;
  if (lane < 8) probs_out[(size_t)n * NE + lane] = p[lane];
  if (lane == 0) {
    int i0 = 0; float v0 = p[0];
#pragma unroll
    for (int e = 1; e < 8; ++e) if (p[e] > v0) { v0 = p[e]; i0 = e; }   // first-max (jax tie rule)
    int i1 = -1; float v1 = -1.f;
#pragma unroll
    for (int e = 0; e < 8; ++e) if (e != i0 && p[e] > v1) { v1 = p[e]; i1 = e; }
    float sw = 1.f / (v0 + v1);
    topi[n] = make_int2(i0, i1);
    topw[n] = make_float2(v0 * sw, v1 * sw);
  }
}

// ================= 3. count: histogram + padded scan + tile map + pad fill =================
__global__ __launch_bounds__(1024) void k_count(
    const int2* __restrict__ topi, int* __restrict__ meta, int* __restrict__ chunk_base,
    int* __restrict__ rows, float* __restrict__ rw) {
  __shared__ int ch[32][8];
  __shared__ int tot[8], poff_s[9], tiles_s[8];
  int t = threadIdx.x;
  int g = t >> 5;
  if (t < 256) ((int*)ch)[t] = 0;
  __syncthreads();
  int c[8] = {0,0,0,0,0,0,0,0};
  int base_tok = t * 8;
#pragma unroll
  for (int i = 0; i < 8; ++i) {
    int2 e = topi[base_tok + i];
#pragma unroll
    for (int k = 0; k < 8; ++k) c[k] += (e.x == k) + (e.y == k);
  }
#pragma unroll
  for (int k = 0; k < 8; ++k) if (c[k]) atomicAdd(&ch[g][k], c[k]);
  __syncthreads();
  if (t < 8) {
    int a = 0;
#pragma unroll
    for (int b = 0; b < 32; ++b) { int v = ch[b][t]; ch[b][t] = a; a += v; }
    tot[t] = a; meta[t] = a;
  }
  __syncthreads();
  if (t == 0) {
    int a = 0, ts = 0;
#pragma unroll
    for (int e = 0; e < 8; ++e) {
      int tiles = (tot[e] + 127) >> 7;
      poff_s[e] = a; tiles_s[e] = tiles;
      meta[16 + e] = a; meta[32 + e] = ts;
      a += tiles << 7; ts += tiles;
    }
    poff_s[8] = a; meta[24] = a; meta[40] = ts;
  }
  __syncthreads();
  if (t < 256) {
    int b = t >> 3, e = t & 7;
    chunk_base[t] = poff_s[e] + ch[b][e];
  }
#pragma unroll
  for (int e = 0; e < 8; ++e) {
    int padn = (tiles_s[e] << 7) - tot[e];
    if (t < padn) {
      int s = poff_s[e] + tot[e] + t;
      rows[s] = 0; rw[s] = 0.f;
    }
  }
}

// ================= 4. slot assignment: LDS atomics only =================
__global__ __launch_bounds__(256) void k_assign(
    const int2* __restrict__ topi, const float2* __restrict__ topw,
    const int* __restrict__ chunk_base,
    int* __restrict__ rows, float* __restrict__ rw, int* __restrict__ slot_of) {
  __shared__ int lcnt[8];
  __shared__ int lbase[8];
  int t = threadIdx.x, b = blockIdx.x;
  if (t < 8) { lcnt[t] = 0; lbase[t] = chunk_base[b * 8 + t]; }
  __syncthreads();
  int n = b * 256 + t;
  int2 ei = topi[n]; float2 wv = topw[n];
  int r0 = atomicAdd(&lcnt[ei.x], 1);
  int r1 = atomicAdd(&lcnt[ei.y], 1);
  int s0 = lbase[ei.x] + r0;
  int s1 = lbase[ei.y] + r1;
  rows[s0] = n; rw[s0] = wv.x; slot_of[2 * n] = s0;
  rows[s1] = n; rw[s1] = wv.y; slot_of[2 * n + 1] = s1;
}

// ================= 5. GEMM1: h = gelu(gather(xbf) @ w1 + b1), h bf16 =================
// grid (136, 8). Tile 128x128, BK=64, XOR-swizzled LDS, async staging.
// Swapped MFMA operands: D = W.T_frag x Token_frag -> lane holds 4 consecutive
// OUTPUT COLS at one token row -> packed 8B stores.
__global__ __launch_bounds__(256) void k_gemm1(
    const unsigned short* __restrict__ xbf, const unsigned short* __restrict__ w1t,
    const float* __restrict__ b1, const int* __restrict__ meta,
    const int* __restrict__ rows, unsigned short* __restrict__ h) {
  int t = blockIdx.x;
  if (t >= meta[40]) return;
  int e = 0;
#pragma unroll
  for (int i = 1; i < 8; ++i) if (t >= meta[32 + i]) e = i;
  int mt = t - meta[32 + e];
  int row0 = meta[16 + e] + (mt << 7);
  int nt = blockIdx.y;
  __shared__ __align__(16) unsigned short As[128 * 64];
  __shared__ __align__(16) unsigned short Bs[128 * 64];
  __shared__ int rows_l[128];
  int tid = threadIdx.x;
  if (tid < 128) rows_l[tid] = rows[row0 + tid];
  __syncthreads();
  int wave = tid >> 6, lane = tid & 63;
  int wr = wave & 1, wc = wave >> 1;
  f32x4 acc[4][4] = {};   // acc[an][am]
  const unsigned short* bBase = w1t + (size_t)e * HID * DIM + (size_t)(nt * 128) * DIM;

  // hoist staging addresses (K-invariant)
  const unsigned short* ga[4]; const unsigned short* gb[4];
#pragma unroll
  for (int j = 0; j < 4; ++j) {
    int s = j * 256 + tid;
    int r = s >> 3;
    int cg = ((s & 7) ^ (r & 7)) << 3;
    ga[j] = xbf + (size_t)rows_l[r] * DIM + cg;
    gb[j] = bBase + (size_t)r * DIM + cg;
  }

  for (int k0 = 0; k0 < DIM; k0 += 64) {
#pragma unroll
    for (int j = 0; j < 4; ++j) {
      async16(&As[(j * 256 + wave * 64) * 8], ga[j] + k0);
      async16(&Bs[(j * 256 + wave * 64) * 8], gb[j] + k0);
    }
    __syncthreads();
#pragma unroll
    for (int kk = 0; kk < 2; ++kk) {
      int ca = kk * 4 + (lane >> 4);       // chunk col for this quad
      short8 tf[4], wf[4];
#pragma unroll
      for (int am = 0; am < 4; ++am) {
        int ra = wr * 64 + am * 16 + (lane & 15);
        tf[am] = *(const short8*)&As[(ra * 8 + (ca ^ (ra & 7))) * 8];
      }
#pragma unroll
      for (int an = 0; an < 4; ++an) {
        int rb = wc * 64 + an * 16 + (lane & 15);
        wf[an] = *(const short8*)&Bs[(rb * 8 + (ca ^ (rb & 7))) * 8];
      }
#pragma unroll
      for (int an = 0; an < 4; ++an)
#pragma unroll
        for (int am = 0; am < 4; ++am)
          acc[an][am] = __builtin_amdgcn_mfma_f32_16x16x32_bf16(wf[an], tf[am], acc[an][am], 0, 0, 0);
    }
    __syncthreads();
  }
  // epilogue: lane holds token row (lane&15) x 4 consecutive cols (quad*4..+3)
  int ml = lane & 15, q = lane >> 4;
#pragma unroll
  for (int am = 0; am < 4; ++am) {
    int slot_r = row0 + wr * 64 + am * 16 + ml;
    unsigned short* hrow = h + (size_t)slot_r * HID;
#pragma unroll
    for (int an = 0; an < 4; ++an) {
      int colb = nt * 128 + wc * 64 + an * 16 + q * 4;
      float4 bias = *(const float4*)&b1[e * HID + colb];
      f32x4 v = acc[an][am];
      float g0 = gelu_f(v[0] + bias.x);
      float g1 = gelu_f(v[1] + bias.y);
      float g2 = gelu_f(v[2] + bias.z);
      float g3 = gelu_f(v[3] + bias.w);
      uint2 pk;
      pk.x = f2bfu(g0) | (f2bfu(g1) << 16);
      pk.y = f2bfu(g2) | (f2bfu(g3) << 16);
      *(uint2*)(hrow + colb) = pk;
    }
  }
}

// ================= 6. GEMM2: y = (h @ w2 + b2) * weight, y bf16 =================
// grid (136, 4). K = HID = 1024. Same swapped-operand structure.
__global__ __launch_bounds__(256) void k_gemm2(
    const unsigned short* __restrict__ h, const unsigned short* __restrict__ w2t,
    const float* __restrict__ b2, const int* __restrict__ meta,
    const float* __restrict__ rw, unsigned short* __restrict__ y) {
  int t = blockIdx.x;
  if (t >= meta[40]) return;
  int e = 0;
#pragma unroll
  for (int i = 1; i < 8; ++i) if (t >= meta[32 + i]) e = i;
  int mt = t - meta[32 + e];
  int row0 = meta[16 + e] + (mt << 7);
  int nt = blockIdx.y;
  __shared__ __align__(16) unsigned short As[128 * 64];
  __shared__ __align__(16) unsigned short Bs[128 * 64];
  int tid = threadIdx.x;
  int wave = tid >> 6, lane = tid & 63;
  int wr = wave & 1, wc = wave >> 1;
  f32x4 acc[4][4] = {};   // acc[an][am]
  const unsigned short* aBase = h + (size_t)row0 * HID;
  const unsigned short* bBase = w2t + (size_t)e * DIM * HID + (size_t)(nt * 128) * HID;

  const unsigned short* ga[4]; const unsigned short* gb[4];
#pragma unroll
  for (int j = 0; j < 4; ++j) {
    int s = j * 256 + tid;
    int r = s >> 3;
    int cg = ((s & 7) ^ (r & 7)) << 3;
    ga[j] = aBase + (size_t)r * HID + cg;
    gb[j] = bBase + (size_t)r * HID + cg;
  }

  for (int k0 = 0; k0 < HID; k0 += 64) {
#pragma unroll
    for (int j = 0; j < 4; ++j) {
      async16(&As[(j * 256 + wave * 64) * 8], ga[j] + k0);
      async16(&Bs[(j * 256 + wave * 64) * 8], gb[j] + k0);
    }
    __syncthreads();
#pragma unroll
    for (int kk = 0; kk < 2; ++kk) {
      int ca = kk * 4 + (lane >> 4);
      short8 tf[4], wf[4];
#pragma unroll
      for (int am = 0; am < 4; ++am) {
        int ra = wr * 64 + am * 16 + (lane & 15);
        tf[am] = *(const short8*)&As[(ra * 8 + (ca ^ (ra & 7))) * 8];
      }
#pragma unroll
      for (int an = 0; an < 4; ++an) {
        int rb = wc * 64 + an * 16 + (lane & 15);
        wf[an] = *(const short8*)&Bs[(rb * 8 + (ca ^ (rb & 7))) * 8];
      }
#pragma unroll
      for (int an = 0; an < 4; ++an)
#pragma unroll
        for (int am = 0; am < 4; ++am)
          acc[an][am] = __builtin_amdgcn_mfma_f32_16x16x32_bf16(wf[an], tf[am], acc[an][am], 0, 0, 0);
    }
    __syncthreads();
  }
  int ml = lane & 15, q = lane >> 4;
#pragma unroll
  for (int am = 0; am < 4; ++am) {
    int slot_r = row0 + wr * 64 + am * 16 + ml;
    float w = rw[slot_r];
    unsigned short* yrow = y + (size_t)slot_r * DIM;
#pragma unroll
    for (int an = 0; an < 4; ++an) {
      int colb = nt * 128 + wc * 64 + an * 16 + q * 4;
      float4 bias = *(const float4*)&b2[e * DIM + colb];
      f32x4 v = acc[an][am];
      uint2 pk;
      pk.x = f2bfu((v[0] + bias.x) * w) | (f2bfu((v[1] + bias.y) * w) << 16);
      pk.y = f2bfu((v[2] + bias.z) * w) | (f2bfu((v[3] + bias.w) * w) << 16);
      *(uint2*)(yrow + colb) = pk;
    }
  }
}

// ================= 7. combine: out[n] = y[slot0] + y[slot1] (bf16 -> fp32) =================
__global__ __launch_bounds__(256) void k_combine(
    const unsigned short* __restrict__ y, const int* __restrict__ slot_of,
    float* __restrict__ out) {
  int t = blockIdx.x * 256 + threadIdx.x;
  int n = t >> 6, c = (t & 63) << 3;
  int s0 = slot_of[2 * n], s1 = slot_of[2 * n + 1];
  uint4 u0 = *(const uint4*)(y + (size_t)s0 * DIM + c);
  uint4 u1 = *(const uint4*)(y + (size_t)s1 * DIM + c);
  float4 o0, o1;
  o0.x = bf2f(u0.x) + bf2f(u1.x); o0.y = bf2f(u0.x >> 16) + bf2f(u1.x >> 16);
  o0.z = bf2f(u0.y) + bf2f(u1.y); o0.w = bf2f(u0.y >> 16) + bf2f(u1.y >> 16);
  o1.x = bf2f(u0.z) + bf2f(u1.z); o1.y = bf2f(u0.z >> 16) + bf2f(u1.z >> 16);
  o1.z = bf2f(u0.w) + bf2f(u1.w); o1.w = bf2f(u0.w >> 16) + bf2f(u1.w >> 16);
  *(float4*)(out + (size_t)n * DIM + c) = o0;
  *(float4*)(out + (size_t)n * DIM + c + 4) = o1;
}

// ================= launch =================
extern "C" void kernel_launch(void* const* d_in, const int* in_sizes, int n_in,
                              void* d_out, int out_size, void* d_ws, size_t ws_size,
                              hipStream_t stream) {
  const float* x  = (const float*)d_in[0];
  const float* gw = (const float*)d_in[1];
  const float* gb = (const float*)d_in[2];
  const float* w1 = (const float*)d_in[3];
  const float* b1 = (const float*)d_in[4];
  const float* w2 = (const float*)d_in[5];
  const float* b2 = (const float*)d_in[6];
  float* out = (float*)d_out;
  char* ws = (char*)d_ws;

  unsigned short* w1t = (unsigned short*)(ws + W1T_OFF);
  unsigned short* w2t = (unsigned short*)(ws + W2T_OFF);
  unsigned short* h   = (unsigned short*)(ws + H_OFF);
  unsigned short* y   = (unsigned short*)(ws + Y_OFF);
  unsigned short* xbf = (unsigned short*)(ws + XBF_OFF);
  int2*   topi    = (int2*)(ws + TOPI_OFF);
  float2* topw    = (float2*)(ws + TOPW_OFF);
  int*    slot_of = (int*)(ws + SLOT_OFF);
  int*    rows    = (int*)(ws + ROWS_OFF);
  float*  rw      = (float*)(ws + RW_OFF);
  int*    meta    = (int*)(ws + CNT_OFF);
  int*    chunk_base = meta + 64;
  float*  probs   = out + (size_t)N_TOK * DIM;

  k_transpose<<<dim3(2048), dim3(256), 0, stream>>>(w1, w2, w1t, w2t);
  k_router   <<<dim3(2048), dim3(256), 0, stream>>>(x, gw, gb, probs, topi, topw, xbf);
  k_count    <<<dim3(1),    dim3(1024), 0, stream>>>(topi, meta, chunk_base, rows, rw);
  k_assign   <<<dim3(32),   dim3(256), 0, stream>>>(topi, topw, chunk_base, rows, rw, slot_of);
  k_gemm1    <<<dim3(136, 8), dim3(256), 0, stream>>>(xbf, w1t, b1, meta, rows, h);
  k_gemm2    <<<dim3(136, 4), dim3(256), 0, stream>>>(h, w2t, b2, meta, rw, y);
  k_combine  <<<dim3(2048), dim3(256), 0, stream>>>(y, slot_of, out);
}

// Round 7
// 214.158 us; speedup vs baseline: 2.6404x; 1.0008x over previous
//
#include <hip/hip_runtime.h>
#include <stdint.h>

// ---------------- problem constants ----------------
#define N_TOK 8192      // B*S = 4*2048
#define DIM   512       // D
#define HID   1024      // H
#define NE    8         // experts
#define NSLOT 16384     // N_TOK * K (K=2)
#define MAXSLOT 17408   // padded slots (<= 136*128)

typedef __attribute__((ext_vector_type(8))) short short8;   // 8 x bf16 (4 VGPRs)
typedef __attribute__((ext_vector_type(4))) float f32x4;    // MFMA C/D frag

// ---------------- workspace layout (bytes) ----------------
#define W1T_OFF  0ull
#define W2T_OFF  8388608ull
#define H_OFF    16777216ull          // 17408*1024*2 = 35651584
#define Y_OFF    52428800ull          // 17408*512*2  = 17825792
#define XBF_OFF  52428800ull          // alias of Y (xbf dead before gemm2 writes y)
#define TOPI_OFF 70254592ull
#define TOPW_OFF 70320128ull
#define SLOT_OFF 70385664ull
#define ROWS_OFF 70451200ull
#define RW_OFF   70520832ull
#define CNT_OFF  70590464ull

__device__ __forceinline__ unsigned int f2bfu(float f) {
  union { float f; unsigned int i; } v; v.f = f;
  unsigned int u = v.i;
  return (u + 0x7FFFu + ((u >> 16) & 1u)) >> 16;  // RNE, bf16 bits in low 16
}
__device__ __forceinline__ float bf2f(unsigned int u) {
  union { unsigned int i; float f; } v; v.i = (u & 0xFFFFu) << 16; return v.f;
}
// fast GELU: x*sigmoid(1.5957691*x*(1+0.044715*x^2)); max |err| vs erf-GELU ~3e-4
__device__ __forceinline__ float gelu_f(float x) {
  float x2 = x * x;
  float u = x * (1.59576912f + 0.07135481f * x2);
  float ez = __expf(-u);
  return x * __builtin_amdgcn_rcpf(1.0f + ez);
}
// async global->LDS, 16B/lane. LDS dest = wave-uniform base + lane*16.
__device__ __forceinline__ void async16(void* lds, const void* g) {
  __builtin_amdgcn_global_load_lds(
      (const __attribute__((address_space(1))) unsigned int*)g,
      (__attribute__((address_space(3))) unsigned int*)lds, 16, 0, 0);
}

// ================= 1. weight transpose + downcast =================
__global__ __launch_bounds__(256) void k_transpose(
    const float* __restrict__ w1, const float* __restrict__ w2,
    unsigned short* __restrict__ w1t, unsigned short* __restrict__ w2t) {
  __shared__ unsigned short tile[64][68];   // +4 pad breaks bank conflicts
  int b = blockIdx.x, tid = threadIdx.x;
  const float* src; unsigned short* dst; int R, C;
  if (b < 1024) { int e = b >> 7; int t = b & 127;
    src = w1 + (size_t)e * 524288; dst = w1t + (size_t)e * 524288; R = 512; C = 1024;
    int tr = t >> 4, tc = t & 15;  // 8 x 16 tiles of 64x64
    src += (size_t)tr * 64 * C + tc * 64; dst += (size_t)tc * 64 * R + tr * 64;
  } else { b -= 1024; int e = b >> 7; int t = b & 127;
    src = w2 + (size_t)e * 524288; dst = w2t + (size_t)e * 524288; R = 1024; C = 512;
    int tr = t >> 3, tc = t & 7;   // 16 x 8 tiles
    src += (size_t)tr * 64 * C + tc * 64; dst += (size_t)tc * 64 * R + tr * 64;
  }
#pragma unroll
  for (int i = 0; i < 4; ++i) {
    int l = i * 256 + tid;
    int r = l >> 4, c4 = (l & 15) << 2;
    float4 v = *(const float4*)(src + (size_t)r * C + c4);
    tile[r][c4 + 0] = (unsigned short)f2bfu(v.x);
    tile[r][c4 + 1] = (unsigned short)f2bfu(v.y);
    tile[r][c4 + 2] = (unsigned short)f2bfu(v.z);
    tile[r][c4 + 3] = (unsigned short)f2bfu(v.w);
  }
  __syncthreads();
#pragma unroll
  for (int i = 0; i < 4; ++i) {
    int l = i * 256 + tid;
    int rr = l >> 4, c4 = (l & 15) << 2;
    ushort4 v;
    v.x = tile[c4 + 0][rr]; v.y = tile[c4 + 1][rr]; v.z = tile[c4 + 2][rr]; v.w = tile[c4 + 3][rr];
    *(ushort4*)(dst + (size_t)rr * R + c4) = v;
  }
}

// ================= 2. router: one wave per token; also emits xbf =================
__global__ __launch_bounds__(256) void k_router(
    const float* __restrict__ x, const float* __restrict__ gw,
    const float* __restrict__ gb, float* __restrict__ probs_out,
    int2* __restrict__ topi, float2* __restrict__ topw,
    unsigned short* __restrict__ xbf) {
  int wave = threadIdx.x >> 6, lane = threadIdx.x & 63;
  int n = blockIdx.x * 4 + wave;
  const float4* xr = (const float4*)(x + (size_t)n * DIM);
  float4 x0 = xr[lane * 2], x1 = xr[lane * 2 + 1];
  float xf[8] = {x0.x, x0.y, x0.z, x0.w, x1.x, x1.y, x1.z, x1.w};
  uint4 pa;
  pa.x = f2bfu(xf[0]) | (f2bfu(xf[1]) << 16);
  pa.y = f2bfu(xf[2]) | (f2bfu(xf[3]) << 16);
  pa.z = f2bfu(xf[4]) | (f2bfu(xf[5]) << 16);
  pa.w = f2bfu(xf[6]) | (f2bfu(xf[7]) << 16);
  *(uint4*)(xbf + (size_t)n * DIM + lane * 8) = pa;
  float acc[8] = {0.f,0.f,0.f,0.f,0.f,0.f,0.f,0.f};
  const float4* gwr = (const float4*)gw;
#pragma unroll
  for (int j = 0; j < 8; ++j) {
    int d = lane * 8 + j;
    float4 g0 = gwr[d * 2], g1 = gwr[d * 2 + 1];
    acc[0] += xf[j] * g0.x; acc[1] += xf[j] * g0.y; acc[2] += xf[j] * g0.z; acc[3] += xf[j] * g0.w;
    acc[4] += xf[j] * g1.x; acc[5] += xf[j] * g1.y; acc[6] += xf[j] * g1.z; acc[7] += xf[j] * g1.w;
  }
#pragma unroll
  for (int o = 1; o < 64; o <<= 1)
#pragma unroll
    for (int e = 0; e < 8; ++e) acc[e] += __shfl_xor(acc[e], o, 64);
  float p[8], mx = -1e30f, s = 0.f;
#pragma unroll
  for (int e = 0; e < 8; ++e) { p[e] = acc[e] + gb[e]; mx = fmaxf(mx, p[e]); }
#pragma unroll
  for (int e = 0; e < 8; ++e) { p[e] = __expf(p[e] - mx); s += p[e]; }
  float inv = 1.f / s;
#pragma unroll
  for (int e = 0; e < 8; ++e) p[e] *= inv;
  if (lane < 8) probs_out[(size_t)n * NE + lane] = p[lane];
  if (lane == 0) {
    int i0 = 0; float v0 = p[0];
#pragma unroll
    for (int e = 1; e < 8; ++e) if (p[e] > v0) { v0 = p[e]; i0 = e; }   // first-max (jax tie rule)
    int i1 = -1; float v1 = -1.f;
#pragma unroll
    for (int e = 0; e < 8; ++e) if (e != i0 && p[e] > v1) { v1 = p[e]; i1 = e; }
    float sw = 1.f / (v0 + v1);
    topi[n] = make_int2(i0, i1);
    topw[n] = make_float2(v0 * sw, v1 * sw);
  }
}

// ================= 3. count: histogram + padded scan + tile map + pad fill =================
__global__ __launch_bounds__(1024) void k_count(
    const int2* __restrict__ topi, int* __restrict__ meta, int* __restrict__ chunk_base,
    int* __restrict__ rows, float* __restrict__ rw) {
  __shared__ int ch[32][8];
  __shared__ int tot[8], poff_s[9], tiles_s[8];
  int t = threadIdx.x;
  int g = t >> 5;
  if (t < 256) ((int*)ch)[t] = 0;
  __syncthreads();
  int c[8] = {0,0,0,0,0,0,0,0};
  int base_tok = t * 8;
#pragma unroll
  for (int i = 0; i < 8; ++i) {
    int2 e = topi[base_tok + i];
#pragma unroll
    for (int k = 0; k < 8; ++k) c[k] += (e.x == k) + (e.y == k);
  }
#pragma unroll
  for (int k = 0; k < 8; ++k) if (c[k]) atomicAdd(&ch[g][k], c[k]);
  __syncthreads();
  if (t < 8) {
    int a = 0;
#pragma unroll
    for (int b = 0; b < 32; ++b) { int v = ch[b][t]; ch[b][t] = a; a += v; }
    tot[t] = a; meta[t] = a;
  }
  __syncthreads();
  if (t == 0) {
    int a = 0, ts = 0;
#pragma unroll
    for (int e = 0; e < 8; ++e) {
      int tiles = (tot[e] + 127) >> 7;
      poff_s[e] = a; tiles_s[e] = tiles;
      meta[16 + e] = a; meta[32 + e] = ts;
      a += tiles << 7; ts += tiles;
    }
    poff_s[8] = a; meta[24] = a; meta[40] = ts;
  }
  __syncthreads();
  if (t < 256) {
    int b = t >> 3, e = t & 7;
    chunk_base[t] = poff_s[e] + ch[b][e];
  }
#pragma unroll
  for (int e = 0; e < 8; ++e) {
    int padn = (tiles_s[e] << 7) - tot[e];
    if (t < padn) {
      int s = poff_s[e] + tot[e] + t;
      rows[s] = 0; rw[s] = 0.f;
    }
  }
}

// ================= 4. slot assignment: LDS atomics only =================
__global__ __launch_bounds__(256) void k_assign(
    const int2* __restrict__ topi, const float2* __restrict__ topw,
    const int* __restrict__ chunk_base,
    int* __restrict__ rows, float* __restrict__ rw, int* __restrict__ slot_of) {
  __shared__ int lcnt[8];
  __shared__ int lbase[8];
  int t = threadIdx.x, b = blockIdx.x;
  if (t < 8) { lcnt[t] = 0; lbase[t] = chunk_base[b * 8 + t]; }
  __syncthreads();
  int n = b * 256 + t;
  int2 ei = topi[n]; float2 wv = topw[n];
  int r0 = atomicAdd(&lcnt[ei.x], 1);
  int r1 = atomicAdd(&lcnt[ei.y], 1);
  int s0 = lbase[ei.x] + r0;
  int s1 = lbase[ei.y] + r1;
  rows[s0] = n; rw[s0] = wv.x; slot_of[2 * n] = s0;
  rows[s1] = n; rw[s1] = wv.y; slot_of[2 * n + 1] = s1;
}

// ================= 5. GEMM1: h = gelu(gather(xbf) @ w1 + b1), h bf16 =================
// grid (8=nt fastest -> XCD-local weight slice, 136=tile). 128x128, BK=64.
// Double-buffered async LDS: prefetch tile k+1 before computing tile k.
__global__ __launch_bounds__(256) void k_gemm1(
    const unsigned short* __restrict__ xbf, const unsigned short* __restrict__ w1t,
    const float* __restrict__ b1, const int* __restrict__ meta,
    const int* __restrict__ rows, unsigned short* __restrict__ h) {
  int t = blockIdx.y;
  if (t >= meta[40]) return;
  int e = 0;
#pragma unroll
  for (int i = 1; i < 8; ++i) if (t >= meta[32 + i]) e = i;
  int mt = t - meta[32 + e];
  int row0 = meta[16 + e] + (mt << 7);
  int nt = blockIdx.x;
  __shared__ __align__(16) unsigned short As[2][8192];
  __shared__ __align__(16) unsigned short Bs[2][8192];
  int tid = threadIdx.x;
  int wave = tid >> 6, lane = tid & 63;
  int wr = wave & 1, wc = wave >> 1;
  f32x4 acc[4][4] = {};   // acc[an][am]
  const unsigned short* bBase = w1t + (size_t)e * HID * DIM + (size_t)(nt * 128) * DIM;

  // K-invariant staging addresses (rows read straight from global; one-time)
  const unsigned short* ga[4]; const unsigned short* gb[4];
#pragma unroll
  for (int j = 0; j < 4; ++j) {
    int s = j * 256 + tid;
    int r = s >> 3;
    int cg = ((s & 7) ^ (r & 7)) << 3;
    ga[j] = xbf + (size_t)rows[row0 + r] * DIM + cg;
    gb[j] = bBase + (size_t)r * DIM + cg;
  }
  int ldst = (wave * 64) * 8;   // wave-uniform LDS base (+ lane*16 implicit)

  // prologue: stage tile 0 into buf 0
#pragma unroll
  for (int j = 0; j < 4; ++j) {
    async16(&As[0][j * 2048 + ldst], ga[j]);
    async16(&Bs[0][j * 2048 + ldst], gb[j]);
  }
  __syncthreads();

  for (int k0 = 0; k0 < DIM; k0 += 64) {
    int cur = (k0 >> 6) & 1, nxt = cur ^ 1;
    if (k0 + 64 < DIM) {
#pragma unroll
      for (int j = 0; j < 4; ++j) {
        async16(&As[nxt][j * 2048 + ldst], ga[j] + k0 + 64);
        async16(&Bs[nxt][j * 2048 + ldst], gb[j] + k0 + 64);
      }
    }
#pragma unroll
    for (int kk = 0; kk < 2; ++kk) {
      int ca = kk * 4 + (lane >> 4);       // chunk col for this quad
      short8 tf[4], wf[4];
#pragma unroll
      for (int am = 0; am < 4; ++am) {
        int ra = wr * 64 + am * 16 + (lane & 15);
        tf[am] = *(const short8*)&As[cur][(ra * 8 + (ca ^ (ra & 7))) * 8];
      }
#pragma unroll
      for (int an = 0; an < 4; ++an) {
        int rb = wc * 64 + an * 16 + (lane & 15);
        wf[an] = *(const short8*)&Bs[cur][(rb * 8 + (ca ^ (rb & 7))) * 8];
      }
#pragma unroll
      for (int an = 0; an < 4; ++an)
#pragma unroll
        for (int am = 0; am < 4; ++am)
          acc[an][am] = __builtin_amdgcn_mfma_f32_16x16x32_bf16(wf[an], tf[am], acc[an][am], 0, 0, 0);
    }
    __syncthreads();   // drains lgkm (reads of cur done) + vmcnt (prefetch arrived)
  }
  // epilogue: lane holds token row (lane&15) x 4 consecutive cols (quad*4..+3)
  int ml = lane & 15, q = lane >> 4;
#pragma unroll
  for (int am = 0; am < 4; ++am) {
    int slot_r = row0 + wr * 64 + am * 16 + ml;
    unsigned short* hrow = h + (size_t)slot_r * HID;
#pragma unroll
    for (int an = 0; an < 4; ++an) {
      int colb = nt * 128 + wc * 64 + an * 16 + q * 4;
      float4 bias = *(const float4*)&b1[e * HID + colb];
      f32x4 v = acc[an][am];
      float g0 = gelu_f(v[0] + bias.x);
      float g1 = gelu_f(v[1] + bias.y);
      float g2 = gelu_f(v[2] + bias.z);
      float g3 = gelu_f(v[3] + bias.w);
      uint2 pk;
      pk.x = f2bfu(g0) | (f2bfu(g1) << 16);
      pk.y = f2bfu(g2) | (f2bfu(g3) << 16);
      *(uint2*)(hrow + colb) = pk;
    }
  }
}

// ================= 6. GEMM2: y = (h @ w2 + b2) * weight, y bf16 =================
// grid (4=nt fastest, 136=tile). K = HID = 1024. Same dbuf structure.
__global__ __launch_bounds__(256) void k_gemm2(
    const unsigned short* __restrict__ h, const unsigned short* __restrict__ w2t,
    const float* __restrict__ b2, const int* __restrict__ meta,
    const float* __restrict__ rw, unsigned short* __restrict__ y) {
  int t = blockIdx.y;
  if (t >= meta[40]) return;
  int e = 0;
#pragma unroll
  for (int i = 1; i < 8; ++i) if (t >= meta[32 + i]) e = i;
  int mt = t - meta[32 + e];
  int row0 = meta[16 + e] + (mt << 7);
  int nt = blockIdx.x;
  __shared__ __align__(16) unsigned short As[2][8192];
  __shared__ __align__(16) unsigned short Bs[2][8192];
  int tid = threadIdx.x;
  int wave = tid >> 6, lane = tid & 63;
  int wr = wave & 1, wc = wave >> 1;
  f32x4 acc[4][4] = {};   // acc[an][am]
  const unsigned short* aBase = h + (size_t)row0 * HID;
  const unsigned short* bBase = w2t + (size_t)e * DIM * HID + (size_t)(nt * 128) * HID;

  const unsigned short* ga[4]; const unsigned short* gb[4];
#pragma unroll
  for (int j = 0; j < 4; ++j) {
    int s = j * 256 + tid;
    int r = s >> 3;
    int cg = ((s & 7) ^ (r & 7)) << 3;
    ga[j] = aBase + (size_t)r * HID + cg;
    gb[j] = bBase + (size_t)r * HID + cg;
  }
  int ldst = (wave * 64) * 8;

#pragma unroll
  for (int j = 0; j < 4; ++j) {
    async16(&As[0][j * 2048 + ldst], ga[j]);
    async16(&Bs[0][j * 2048 + ldst], gb[j]);
  }
  __syncthreads();

  for (int k0 = 0; k0 < HID; k0 += 64) {
    int cur = (k0 >> 6) & 1, nxt = cur ^ 1;
    if (k0 + 64 < HID) {
#pragma unroll
      for (int j = 0; j < 4; ++j) {
        async16(&As[nxt][j * 2048 + ldst], ga[j] + k0 + 64);
        async16(&Bs[nxt][j * 2048 + ldst], gb[j] + k0 + 64);
      }
    }
#pragma unroll
    for (int kk = 0; kk < 2; ++kk) {
      int ca = kk * 4 + (lane >> 4);
      short8 tf[4], wf[4];
#pragma unroll
      for (int am = 0; am < 4; ++am) {
        int ra = wr * 64 + am * 16 + (lane & 15);
        tf[am] = *(const short8*)&As[cur][(ra * 8 + (ca ^ (ra & 7))) * 8];
      }
#pragma unroll
      for (int an = 0; an < 4; ++an) {
        int rb = wc * 64 + an * 16 + (lane & 15);
        wf[an] = *(const short8*)&Bs[cur][(rb * 8 + (ca ^ (rb & 7))) * 8];
      }
#pragma unroll
      for (int an = 0; an < 4; ++an)
#pragma unroll
        for (int am = 0; am < 4; ++am)
          acc[an][am] = __builtin_amdgcn_mfma_f32_16x16x32_bf16(wf[an], tf[am], acc[an][am], 0, 0, 0);
    }
    __syncthreads();
  }
  int ml = lane & 15, q = lane >> 4;
#pragma unroll
  for (int am = 0; am < 4; ++am) {
    int slot_r = row0 + wr * 64 + am * 16 + ml;
    float w = rw[slot_r];
    unsigned short* yrow = y + (size_t)slot_r * DIM;
#pragma unroll
    for (int an = 0; an < 4; ++an) {
      int colb = nt * 128 + wc * 64 + an * 16 + q * 4;
      float4 bias = *(const float4*)&b2[e * DIM + colb];
      f32x4 v = acc[an][am];
      uint2 pk;
      pk.x = f2bfu((v[0] + bias.x) * w) | (f2bfu((v[1] + bias.y) * w) << 16);
      pk.y = f2bfu((v[2] + bias.z) * w) | (f2bfu((v[3] + bias.w) * w) << 16);
      *(uint2*)(yrow + colb) = pk;
    }
  }
}

// ================= 7. combine: out[n] = y[slot0] + y[slot1] (bf16 -> fp32) =================
__global__ __launch_bounds__(256) void k_combine(
    const unsigned short* __restrict__ y, const int* __restrict__ slot_of,
    float* __restrict__ out) {
  int t = blockIdx.x * 256 + threadIdx.x;
  int n = t >> 6, c = (t & 63) << 3;
  int s0 = slot_of[2 * n], s1 = slot_of[2 * n + 1];
  uint4 u0 = *(const uint4*)(y + (size_t)s0 * DIM + c);
  uint4 u1 = *(const uint4*)(y + (size_t)s1 * DIM + c);
  float4 o0, o1;
  o0.x = bf2f(u0.x) + bf2f(u1.x); o0.y = bf2f(u0.x >> 16) + bf2f(u1.x >> 16);
  o0.z = bf2f(u0.y) + bf2f(u1.y); o0.w = bf2f(u0.y >> 16) + bf2f(u1.y >> 16);
  o1.x = bf2f(u0.z) + bf2f(u1.z); o1.y = bf2f(u0.z >> 16) + bf2f(u1.z >> 16);
  o1.z = bf2f(u0.w) + bf2f(u1.w); o1.w = bf2f(u0.w >> 16) + bf2f(u1.w >> 16);
  *(float4*)(out + (size_t)n * DIM + c) = o0;
  *(float4*)(out + (size_t)n * DIM + c + 4) = o1;
}

// ================= launch =================
extern "C" void kernel_launch(void* const* d_in, const int* in_sizes, int n_in,
                              void* d_out, int out_size, void* d_ws, size_t ws_size,
                              hipStream_t stream) {
  const float* x  = (const float*)d_in[0];
  const float* gw = (const float*)d_in[1];
  const float* gb = (const float*)d_in[2];
  const float* w1 = (const float*)d_in[3];
  const float* b1 = (const float*)d_in[4];
  const float* w2 = (const float*)d_in[5];
  const float* b2 = (const float*)d_in[6];
  float* out = (float*)d_out;
  char* ws = (char*)d_ws;

  unsigned short* w1t = (unsigned short*)(ws + W1T_OFF);
  unsigned short* w2t = (unsigned short*)(ws + W2T_OFF);
  unsigned short* h   = (unsigned short*)(ws + H_OFF);
  unsigned short* y   = (unsigned short*)(ws + Y_OFF);
  unsigned short* xbf = (unsigned short*)(ws + XBF_OFF);
  int2*   topi    = (int2*)(ws + TOPI_OFF);
  float2* topw    = (float2*)(ws + TOPW_OFF);
  int*    slot_of = (int*)(ws + SLOT_OFF);
  int*    rows    = (int*)(ws + ROWS_OFF);
  float*  rw      = (float*)(ws + RW_OFF);
  int*    meta    = (int*)(ws + CNT_OFF);
  int*    chunk_base = meta + 64;
  float*  probs   = out + (size_t)N_TOK * DIM;

  k_transpose<<<dim3(2048), dim3(256), 0, stream>>>(w1, w2, w1t, w2t);
  k_router   <<<dim3(2048), dim3(256), 0, stream>>>(x, gw, gb, probs, topi, topw, xbf);
  k_count    <<<dim3(1),    dim3(1024), 0, stream>>>(topi, meta, chunk_base, rows, rw);
  k_assign   <<<dim3(32),   dim3(256), 0, stream>>>(topi, topw, chunk_base, rows, rw, slot_of);
  k_gemm1    <<<dim3(8, 136), dim3(256), 0, stream>>>(xbf, w1t, b1, meta, rows, h);
  k_gemm2    <<<dim3(4, 136), dim3(256), 0, stream>>>(h, w2t, b2, meta, rw, y);
  k_combine  <<<dim3(2048), dim3(256), 0, stream>>>(y, slot_of, out);
}